// Round 1
// baseline (644.878 us; speedup 1.0000x reference)
//
#include <hip/hip_runtime.h>
#include <cstdint>
#include <cstddef>

#define DEV __device__ __forceinline__

static constexpr int NN  = 50000;
static constexpr int EE  = 600000;
static constexpr int ET  = 650000;   // EE + NN self loops

DEV float wsum(float v){
  #pragma unroll
  for (int o = 32; o > 0; o >>= 1) v += __shfl_xor(v, o, 64);
  return v;
}
DEV float wmaxr(float v){
  #pragma unroll
  for (int o = 32; o > 0; o >>= 1) v = fmaxf(v, __shfl_xor(v, o, 64));
  return v;
}
DEV float lrelu(float x){ return x > 0.f ? x : 0.2f * x; }
DEV float eluf(float x){ return x > 0.f ? x : expm1f(x); }
DEV float ln64(float v, const float* g, const float* b, int lane){
  float mu  = wsum(v) * (1.f/64.f);
  float d   = v - mu;
  float var = wsum(d*d) * (1.f/64.f);
  return d * rsqrtf(var + 1e-5f) * g[lane] + b[lane];
}

// ---------------- CSR build ----------------
__global__ void degree_kernel(const int* __restrict__ ei, int* __restrict__ deg){
  int e = blockIdx.x * blockDim.x + threadIdx.x;
  if (e >= ET) return;
  int dst = (e < EE) ? ei[EE + e] : (e - EE);
  atomicAdd(&deg[dst], 1);
}

__global__ __launch_bounds__(1024) void scan_kernel(const int* __restrict__ deg,
                                                    int* __restrict__ off,
                                                    int* __restrict__ cur, int n){
  __shared__ int wsh[16];
  __shared__ int s_run;
  int tid = threadIdx.x, lane = tid & 63, w = tid >> 6;
  if (tid == 0) s_run = 0;
  __syncthreads();
  const int PER = 8, CH = 1024 * PER;
  for (int base = 0; base < n; base += CH){
    int v[PER]; int s = 0;
    int i0 = base + tid * PER;
    #pragma unroll
    for (int p = 0; p < PER; p++){ int i = i0 + p; v[p] = (i < n) ? deg[i] : 0; s += v[p]; }
    int sc = s;
    #pragma unroll
    for (int d = 1; d < 64; d <<= 1){ int t = __shfl_up(sc, d, 64); if (lane >= d) sc += t; }
    if (lane == 63) wsh[w] = sc;
    __syncthreads();
    int run = s_run;
    int woff = 0;
    for (int k = 0; k < w; k++) woff += wsh[k];
    int excl = run + woff + sc - s;
    #pragma unroll
    for (int p = 0; p < PER; p++){
      int i = i0 + p;
      if (i < n){ off[i] = excl; cur[i] = excl; }
      excl += v[p];
    }
    __syncthreads();
    if (tid == 0){ int tot = 0; for (int k = 0; k < 16; k++) tot += wsh[k]; s_run = run + tot; }
    __syncthreads();
  }
  if (threadIdx.x == 0) off[n] = s_run;
}

__global__ void fill_csr(const int* __restrict__ ei, int* __restrict__ cur,
                         int* __restrict__ csr_src, int* __restrict__ csr_eid){
  int e = blockIdx.x * blockDim.x + threadIdx.x;
  if (e >= ET) return;
  int src, dst;
  if (e < EE){ src = ei[e]; dst = ei[EE + e]; } else { src = dst = e - EE; }
  int pos = atomicAdd(&cur[dst], 1);
  csr_src[pos] = src;
  csr_eid[pos] = e;
}

// ---------------- f32 tiled GEMM: C[M,N] = A[M,K] @ B[K,N] ----------------
// BM=64,BN=64,BK=32, 256 threads, 4x4 per thread. N,K multiples of tile dims.
__global__ __launch_bounds__(256) void gemm_f32(const float* __restrict__ A,
                                                const float* __restrict__ B,
                                                float* __restrict__ C,
                                                int M, int N, int K){
  constexpr int BM = 64, BN = 64, BK = 32;
  __shared__ float As[BK][BM + 1];
  __shared__ float Bs[BK][BN];
  int tid = threadIdx.x;
  int tx = tid & 15;        // 16
  int ty = tid >> 4;        // 16
  int row0 = blockIdx.y * BM;
  int col0 = blockIdx.x * BN;
  float acc[4][4] = {};
  for (int k0 = 0; k0 < K; k0 += BK){
    // A tile: 64x32, float4 loads (2 per thread)
    #pragma unroll
    for (int l = 0; l < 2; l++){
      int i  = tid + l * 256;          // over 512 float4 slots
      int r  = i >> 3;                 // 0..63
      int c4 = (i & 7) * 4;            // 0,4,..,28
      float4 v = make_float4(0.f, 0.f, 0.f, 0.f);
      if (row0 + r < M)
        v = *(const float4*)&A[(size_t)(row0 + r) * K + k0 + c4];
      As[c4 + 0][r] = v.x; As[c4 + 1][r] = v.y; As[c4 + 2][r] = v.z; As[c4 + 3][r] = v.w;
    }
    // B tile: 32x64, float4 loads (2 per thread)
    #pragma unroll
    for (int l = 0; l < 2; l++){
      int i  = tid + l * 256;
      int r  = i >> 4;                 // 0..31
      int c4 = (i & 15) * 4;
      float4 v = *(const float4*)&B[(size_t)(k0 + r) * N + col0 + c4];
      *(float4*)&Bs[r][c4] = v;
    }
    __syncthreads();
    #pragma unroll
    for (int kk = 0; kk < BK; kk++){
      float a[4];
      #pragma unroll
      for (int i = 0; i < 4; i++) a[i] = As[kk][ty * 4 + i];
      float4 bv = *(const float4*)&Bs[kk][tx * 4];
      float b[4] = {bv.x, bv.y, bv.z, bv.w};
      #pragma unroll
      for (int i = 0; i < 4; i++)
        #pragma unroll
        for (int j = 0; j < 4; j++)
          acc[i][j] = fmaf(a[i], b[j], acc[i][j]);
    }
    __syncthreads();
  }
  #pragma unroll
  for (int i = 0; i < 4; i++){
    int r = row0 + ty * 4 + i;
    if (r < M){
      float4 v = make_float4(acc[i][0], acc[i][1], acc[i][2], acc[i][3]);
      *(float4*)&C[(size_t)r * N + col0 + tx * 4] = v;
    }
  }
}

// ---------------- attention dot products ----------------
// layer1: H1 [N,256] viewed as [N,4,64]; es/ed [N,4]
__global__ __launch_bounds__(256) void att1_kernel(const float* __restrict__ H1,
                                                   const float* __restrict__ asrc,
                                                   const float* __restrict__ adst,
                                                   float* __restrict__ es,
                                                   float* __restrict__ ed, int n){
  int wid  = (blockIdx.x * blockDim.x + threadIdx.x) >> 6;
  int lane = threadIdx.x & 63;
  if (wid >= n) return;
  const float* row = H1 + (size_t)wid * 256;
  float s[4], d[4];
  #pragma unroll
  for (int h = 0; h < 4; h++){
    float hv = row[h * 64 + lane];
    s[h] = hv * asrc[h * 64 + lane];
    d[h] = hv * adst[h * 64 + lane];
  }
  #pragma unroll
  for (int h = 0; h < 4; h++){ s[h] = wsum(s[h]); d[h] = wsum(d[h]); }
  if (lane == 0){
    #pragma unroll
    for (int h = 0; h < 4; h++){ es[wid * 4 + h] = s[h]; ed[wid * 4 + h] = d[h]; }
  }
}

__global__ __launch_bounds__(256) void att2_kernel(const float* __restrict__ H2,
                                                   const float* __restrict__ asrc,
                                                   const float* __restrict__ adst,
                                                   float* __restrict__ es,
                                                   float* __restrict__ ed, int n){
  int wid  = (blockIdx.x * blockDim.x + threadIdx.x) >> 6;
  int lane = threadIdx.x & 63;
  if (wid >= n) return;
  float hv = H2[(size_t)wid * 64 + lane];
  float s = wsum(hv * asrc[lane]);
  float d = wsum(hv * adst[lane]);
  if (lane == 0){ es[wid] = s; ed[wid] = d; }
}

// ---------------- layer-1 aggregation: softmax + weighted sum + bias + elu + LN256 ----------------
__global__ __launch_bounds__(256) void agg1_kernel(const int* __restrict__ off,
                                                   const int* __restrict__ csr_src,
                                                   const float* __restrict__ H1,
                                                   const float* __restrict__ es,
                                                   const float* __restrict__ ed,
                                                   const float* __restrict__ b1,
                                                   const float* __restrict__ lng,
                                                   const float* __restrict__ lnb,
                                                   float* __restrict__ h1out, int n){
  int wid  = (blockIdx.x * blockDim.x + threadIdx.x) >> 6;
  int lane = threadIdx.x & 63;
  if (wid >= n) return;
  int s0  = off[wid];
  int deg = off[wid + 1] - s0;
  const float4 edv = *(const float4*)(ed + (size_t)wid * 4);

  // pass 1: per-head max (edge-parallel across lanes)
  float m0 = -1e30f, m1 = -1e30f, m2 = -1e30f, m3 = -1e30f;
  for (int j = lane; j < deg; j += 64){
    int src = csr_src[s0 + j];
    float4 e4 = *(const float4*)(es + (size_t)src * 4);
    m0 = fmaxf(m0, lrelu(e4.x + edv.x));
    m1 = fmaxf(m1, lrelu(e4.y + edv.y));
    m2 = fmaxf(m2, lrelu(e4.z + edv.z));
    m3 = fmaxf(m3, lrelu(e4.w + edv.w));
  }
  m0 = wmaxr(m0); m1 = wmaxr(m1); m2 = wmaxr(m2); m3 = wmaxr(m3);

  // pass 2: channel-parallel aggregation; ex computed redundantly per lane
  float acc0 = 0.f, acc1 = 0.f, acc2 = 0.f, acc3 = 0.f;
  float den0 = 0.f, den1 = 0.f, den2 = 0.f, den3 = 0.f;
  for (int j = 0; j < deg; j++){
    int src = csr_src[s0 + j];
    float4 e4 = *(const float4*)(es + (size_t)src * 4);
    float x0 = __expf(lrelu(e4.x + edv.x) - m0);
    float x1 = __expf(lrelu(e4.y + edv.y) - m1);
    float x2 = __expf(lrelu(e4.z + edv.z) - m2);
    float x3 = __expf(lrelu(e4.w + edv.w) - m3);
    den0 += x0; den1 += x1; den2 += x2; den3 += x3;
    const float* hp = H1 + (size_t)src * 256;
    acc0 = fmaf(hp[lane],        x0, acc0);
    acc1 = fmaf(hp[64 + lane],   x1, acc1);
    acc2 = fmaf(hp[128 + lane],  x2, acc2);
    acc3 = fmaf(hp[192 + lane],  x3, acc3);
  }
  float v0 = acc0 / (den0 + 1e-16f) + b1[lane];
  float v1 = acc1 / (den1 + 1e-16f) + b1[64 + lane];
  float v2 = acc2 / (den2 + 1e-16f) + b1[128 + lane];
  float v3 = acc3 / (den3 + 1e-16f) + b1[192 + lane];
  v0 = eluf(v0); v1 = eluf(v1); v2 = eluf(v2); v3 = eluf(v3);
  float mu = wsum(v0 + v1 + v2 + v3) * (1.f/256.f);
  float q  = (v0-mu)*(v0-mu) + (v1-mu)*(v1-mu) + (v2-mu)*(v2-mu) + (v3-mu)*(v3-mu);
  float rstd = rsqrtf(wsum(q) * (1.f/256.f) + 1e-5f);
  float* o = h1out + (size_t)wid * 256;
  o[lane]        = (v0-mu)*rstd*lng[lane]        + lnb[lane];
  o[64 + lane]   = (v1-mu)*rstd*lng[64 + lane]   + lnb[64 + lane];
  o[128 + lane]  = (v2-mu)*rstd*lng[128 + lane]  + lnb[128 + lane];
  o[192 + lane]  = (v3-mu)*rstd*lng[192 + lane]  + lnb[192 + lane];
}

// ---------------- layer-2 aggregation (1 head): softmax + alpha out + weighted sum + bias + LN64 ----------------
__global__ __launch_bounds__(256) void agg2_kernel(const int* __restrict__ off,
                                                   const int* __restrict__ csr_src,
                                                   const int* __restrict__ csr_eid,
                                                   const float* __restrict__ H2,
                                                   const float* __restrict__ es,
                                                   const float* __restrict__ ed,
                                                   const float* __restrict__ b2,
                                                   const float* __restrict__ lng,
                                                   const float* __restrict__ lnb,
                                                   float* __restrict__ h2out,
                                                   float* __restrict__ alpha_out, int n){
  int wid  = (blockIdx.x * blockDim.x + threadIdx.x) >> 6;
  int lane = threadIdx.x & 63;
  if (wid >= n) return;
  int s0  = off[wid];
  int deg = off[wid + 1] - s0;
  float edv = ed[wid];

  float m = -1e30f;
  for (int j = lane; j < deg; j += 64){
    int src = csr_src[s0 + j];
    m = fmaxf(m, lrelu(es[src] + edv));
  }
  m = wmaxr(m);

  float den = 0.f;
  for (int j = lane; j < deg; j += 64){
    int src = csr_src[s0 + j];
    den += __expf(lrelu(es[src] + edv) - m);
  }
  den = wsum(den) + 1e-16f;

  float acc = 0.f;
  for (int j = 0; j < deg; j++){
    int src = csr_src[s0 + j];
    float a = __expf(lrelu(es[src] + edv) - m) / den;
    if (lane == 0) alpha_out[csr_eid[s0 + j]] = a;
    acc = fmaf(H2[(size_t)src * 64 + lane], a, acc);
  }
  float v  = acc + b2[lane];
  float mu = wsum(v) * (1.f/64.f);
  float d  = v - mu;
  float rstd = rsqrtf(wsum(d*d) * (1.f/64.f) + 1e-5f);
  h2out[(size_t)wid * 64 + lane] = d * rstd * lng[lane] + lnb[lane];
}

// ---------------- head: step/sentence MLP + dueling head ----------------
__global__ __launch_bounds__(64) void head_kernel(const float* __restrict__ semb,
                                                  const int* __restrict__ active,
                                                  const int* __restrict__ step,
                                                  const float* __restrict__ fc0w, const float* __restrict__ fc0b,
                                                  const float* __restrict__ fc1w, const float* __restrict__ fc1b,
                                                  const float* __restrict__ fc2w, const float* __restrict__ fc2b,
                                                  const float* __restrict__ fc3w, const float* __restrict__ fc3b,
                                                  const float* __restrict__ valw, const float* __restrict__ valb,
                                                  const float* __restrict__ advw, const float* __restrict__ advb,
                                                  const float* __restrict__ lnhg, const float* __restrict__ lnhb,
                                                  const float* __restrict__ lnfg, const float* __restrict__ lnfb,
                                                  const float* __restrict__ h2,
                                                  float* __restrict__ out){
  int t = threadIdx.x;  // one wave of 64
  __shared__ float sh[128];

  // step embedding
  float sval = (float)(step[0] + 1) * 0.01f;
  float stepsv = ln64(fmaxf(fmaf(sval, fc0w[t], fc0b[t]), 0.f), lnhg, lnhb, t);

  // fc1: 768 -> 64
  float acc = fc1b[t];
  #pragma unroll 8
  for (int k = 0; k < 768; k++) acc = fmaf(semb[k], fc1w[k * 64 + t], acc);
  float sentv = ln64(fmaxf(acc, 0.f), lnhg, lnhb, t) + stepsv;
  sh[t] = sentv;
  __syncthreads();
  float acc2 = fc2b[t];
  #pragma unroll 8
  for (int k = 0; k < 64; k++) acc2 = fmaf(sh[k], fc2w[k * 64 + t], acc2);
  __syncthreads();
  float sent2 = ln64(fmaxf(acc2, 0.f), lnhg, lnhb, t);

  // anf = concat(h2[active], sent2), LN over 128
  float a0 = h2[(size_t)active[0] * 64 + t];
  float a1 = sent2;
  float mu = wsum(a0 + a1) * (1.f/128.f);
  float q  = (a0-mu)*(a0-mu) + (a1-mu)*(a1-mu);
  float rstd = rsqrtf(wsum(q) * (1.f/128.f) + 1e-5f);
  float n0 = (a0-mu)*rstd*lnfg[t]      + lnfb[t];
  float n1 = (a1-mu)*rstd*lnfg[64 + t] + lnfb[64 + t];
  sh[t] = n0; sh[64 + t] = n1;
  __syncthreads();

  // fc3: 128 -> 64, relu, LN
  float acc3 = fc3b[t];
  #pragma unroll 8
  for (int k = 0; k < 128; k++) acc3 = fmaf(sh[k], fc3w[k * 64 + t], acc3);
  float a2v = ln64(fmaxf(acc3, 0.f), lnhg, lnhb, t);
  __syncthreads();
  sh[t] = a2v;
  __syncthreads();

  // val (64->1), adv (64->32)
  float val = wsum(a2v * valw[t]) + valb[0];
  float advv = 0.f;
  if (t < 32){
    advv = advb[t];
    #pragma unroll 8
    for (int k = 0; k < 64; k++) advv = fmaf(sh[k], advw[k * 32 + t], advv);
  }
  float am = wsum(t < 32 ? advv : 0.f) * (1.f/32.f);
  if (t < 32) out[t] = tanhf(val + advv - am);
}

extern "C" void kernel_launch(void* const* d_in, const int* in_sizes, int n_in,
                              void* d_out, int out_size, void* d_ws, size_t ws_size,
                              hipStream_t stream) {
  const float* x     = (const float*)d_in[0];
  const int*   ei    = (const int*)  d_in[1];
  const float* semb  = (const float*)d_in[2];
  const int*   act   = (const int*)  d_in[3];
  const int*   step  = (const int*)  d_in[4];
  const float* W1    = (const float*)d_in[5];
  const float* as1   = (const float*)d_in[6];
  const float* ad1   = (const float*)d_in[7];
  const float* b1    = (const float*)d_in[8];
  const float* W2    = (const float*)d_in[9];
  const float* as2   = (const float*)d_in[10];
  const float* ad2   = (const float*)d_in[11];
  const float* b2    = (const float*)d_in[12];
  const float* fc0w  = (const float*)d_in[13];
  const float* fc0b  = (const float*)d_in[14];
  const float* fc1w  = (const float*)d_in[15];
  const float* fc1b  = (const float*)d_in[16];
  const float* fc2w  = (const float*)d_in[17];
  const float* fc2b  = (const float*)d_in[18];
  const float* fc3w  = (const float*)d_in[19];
  const float* fc3b  = (const float*)d_in[20];
  const float* valw  = (const float*)d_in[21];
  const float* valb  = (const float*)d_in[22];
  const float* advw  = (const float*)d_in[23];
  const float* advb  = (const float*)d_in[24];
  const float* lnhg  = (const float*)d_in[25];
  const float* lnhb  = (const float*)d_in[26];
  const float* lnfg  = (const float*)d_in[27];
  const float* lnfb  = (const float*)d_in[28];
  const float* lnag  = (const float*)d_in[29];
  const float* lnab  = (const float*)d_in[30];

  char* ws = (char*)d_ws;
  size_t o = 0;
  auto alloc = [&](size_t bytes) -> void* {
    o = (o + 255) & ~(size_t)255;
    void* p = ws + o;
    o += bytes;
    return p;
  };
  int*   deg     = (int*)  alloc((size_t)(NN + 1) * 4);
  int*   off     = (int*)  alloc((size_t)(NN + 1) * 4);
  int*   cur     = (int*)  alloc((size_t)NN * 4);
  int*   csr_src = (int*)  alloc((size_t)ET * 4);
  int*   csr_eid = (int*)  alloc((size_t)ET * 4);
  float* H1      = (float*)alloc((size_t)NN * 256 * 4);
  float* h1      = (float*)alloc((size_t)NN * 256 * 4);
  float* es1     = (float*)alloc((size_t)NN * 16);
  float* ed1     = (float*)alloc((size_t)NN * 16);
  // aliases (lifetimes don't overlap with their hosts)
  float* H2  = H1;    // [N,64], written by GEMM2 which reads h1
  float* es2 = es1;
  float* ed2 = ed1;

  float* logits    = (float*)d_out;
  float* h2out     = (float*)d_out + 32;
  float* alpha_out = (float*)d_out + 32 + (size_t)NN * 64;

  // CSR build
  hipMemsetAsync(deg, 0, (size_t)NN * 4, stream);
  degree_kernel<<<(ET + 255) / 256, 256, 0, stream>>>(ei, deg);
  scan_kernel<<<1, 1024, 0, stream>>>(deg, off, cur, NN);
  fill_csr<<<(ET + 255) / 256, 256, 0, stream>>>(ei, cur, csr_src, csr_eid);

  // layer 1
  gemm_f32<<<dim3(256 / 64, (NN + 63) / 64), 256, 0, stream>>>(x, W1, H1, NN, 256, 128);
  att1_kernel<<<NN / 4, 256, 0, stream>>>(H1, as1, ad1, es1, ed1, NN);
  agg1_kernel<<<NN / 4, 256, 0, stream>>>(off, csr_src, H1, es1, ed1, b1, lnag, lnab, h1, NN);

  // layer 2
  gemm_f32<<<dim3(1, (NN + 63) / 64), 256, 0, stream>>>(h1, W2, H2, NN, 64, 256);
  att2_kernel<<<NN / 4, 256, 0, stream>>>(H2, as2, ad2, es2, ed2, NN);
  agg2_kernel<<<NN / 4, 256, 0, stream>>>(off, csr_src, csr_eid, H2, es2, ed2, b2,
                                          lnhg, lnhb, h2out, alpha_out, NN);

  // head
  head_kernel<<<1, 64, 0, stream>>>(semb, act, step,
                                    fc0w, fc0b, fc1w, fc1b, fc2w, fc2b, fc3w, fc3b,
                                    valw, valb, advw, advb,
                                    lnhg, lnhb, lnfg, lnfb,
                                    h2out, logits);
}

// Round 2
// 544.275 us; speedup vs baseline: 1.1848x; 1.1848x over previous
//
#include <hip/hip_runtime.h>
#include <cstdint>
#include <cstddef>

#define DEV __device__ __forceinline__

static constexpr int NN  = 50000;
static constexpr int EE  = 600000;
static constexpr int ET  = 650000;   // EE + NN self loops

DEV float wsum(float v){
  #pragma unroll
  for (int o = 32; o > 0; o >>= 1) v += __shfl_xor(v, o, 64);
  return v;
}
DEV float wmaxr(float v){
  #pragma unroll
  for (int o = 32; o > 0; o >>= 1) v = fmaxf(v, __shfl_xor(v, o, 64));
  return v;
}
DEV float lrelu(float x){ return x > 0.f ? x : 0.2f * x; }
DEV float eluf(float x){ return x > 0.f ? x : expm1f(x); }
DEV float ln64(float v, const float* g, const float* b, int lane){
  float mu  = wsum(v) * (1.f/64.f);
  float d   = v - mu;
  float var = wsum(d*d) * (1.f/64.f);
  return d * rsqrtf(var + 1e-5f) * g[lane] + b[lane];
}

// ---------------- CSR build ----------------
__global__ void degree_kernel(const int* __restrict__ ei, int* __restrict__ deg){
  int e = blockIdx.x * blockDim.x + threadIdx.x;
  if (e >= ET) return;
  int dst = (e < EE) ? ei[EE + e] : (e - EE);
  atomicAdd(&deg[dst], 1);
}

__global__ __launch_bounds__(1024) void scan_kernel(const int* __restrict__ deg,
                                                    int* __restrict__ off,
                                                    int* __restrict__ cur, int n){
  __shared__ int wsh[16];
  __shared__ int s_run;
  int tid = threadIdx.x, lane = tid & 63, w = tid >> 6;
  if (tid == 0) s_run = 0;
  __syncthreads();
  const int PER = 8, CH = 1024 * PER;
  for (int base = 0; base < n; base += CH){
    int v[PER]; int s = 0;
    int i0 = base + tid * PER;
    #pragma unroll
    for (int p = 0; p < PER; p++){ int i = i0 + p; v[p] = (i < n) ? deg[i] : 0; s += v[p]; }
    int sc = s;
    #pragma unroll
    for (int d = 1; d < 64; d <<= 1){ int t = __shfl_up(sc, d, 64); if (lane >= d) sc += t; }
    if (lane == 63) wsh[w] = sc;
    __syncthreads();
    int run = s_run;
    int woff = 0;
    for (int k = 0; k < w; k++) woff += wsh[k];
    int excl = run + woff + sc - s;
    #pragma unroll
    for (int p = 0; p < PER; p++){
      int i = i0 + p;
      if (i < n){ off[i] = excl; cur[i] = excl; }
      excl += v[p];
    }
    __syncthreads();
    if (tid == 0){ int tot = 0; for (int k = 0; k < 16; k++) tot += wsh[k]; s_run = run + tot; }
    __syncthreads();
  }
  if (threadIdx.x == 0) off[n] = s_run;
}

__global__ void fill_csr(const int* __restrict__ ei, int* __restrict__ cur,
                         int* __restrict__ csr_src, int* __restrict__ csr_eid){
  int e = blockIdx.x * blockDim.x + threadIdx.x;
  if (e >= ET) return;
  int src, dst;
  if (e < EE){ src = ei[e]; dst = ei[EE + e]; } else { src = dst = e - EE; }
  int pos = atomicAdd(&cur[dst], 1);
  csr_src[pos] = src;
  csr_eid[pos] = e;
}

// ---------------- f32 tiled GEMM with fused attention-dot epilogue ----------------
// C[M,N] = A[M,K] @ B[K,N]; BM=64,BN=64,BK=32; 256 thr, 4x4/thread.
// Each 64-wide col block == one head; epilogue reduces es/ed for that head.
__global__ __launch_bounds__(256) void gemm_att(const float* __restrict__ A,
                                                const float* __restrict__ B,
                                                float* __restrict__ C,
                                                int M, int N, int K,
                                                const float* __restrict__ asrc,
                                                const float* __restrict__ adst,
                                                float* __restrict__ es,
                                                float* __restrict__ ed, int nh){
  constexpr int BM = 64, BN = 64, BK = 32;
  __shared__ float As[BK][BM + 1];
  __shared__ float Bs[BK][BN];
  int tid = threadIdx.x;
  int tx = tid & 15;        // 16
  int ty = tid >> 4;        // 16
  int row0 = blockIdx.y * BM;
  int col0 = blockIdx.x * BN;
  int head = blockIdx.x;
  float acc[4][4] = {};
  for (int k0 = 0; k0 < K; k0 += BK){
    #pragma unroll
    for (int l = 0; l < 2; l++){
      int i  = tid + l * 256;
      int r  = i >> 3;
      int c4 = (i & 7) * 4;
      float4 v = make_float4(0.f, 0.f, 0.f, 0.f);
      if (row0 + r < M)
        v = *(const float4*)&A[(size_t)(row0 + r) * K + k0 + c4];
      As[c4 + 0][r] = v.x; As[c4 + 1][r] = v.y; As[c4 + 2][r] = v.z; As[c4 + 3][r] = v.w;
    }
    #pragma unroll
    for (int l = 0; l < 2; l++){
      int i  = tid + l * 256;
      int r  = i >> 4;
      int c4 = (i & 15) * 4;
      float4 v = *(const float4*)&B[(size_t)(k0 + r) * N + col0 + c4];
      *(float4*)&Bs[r][c4] = v;
    }
    __syncthreads();
    #pragma unroll
    for (int kk = 0; kk < BK; kk++){
      float a[4];
      #pragma unroll
      for (int i = 0; i < 4; i++) a[i] = As[kk][ty * 4 + i];
      float4 bv = *(const float4*)&Bs[kk][tx * 4];
      float b[4] = {bv.x, bv.y, bv.z, bv.w};
      #pragma unroll
      for (int i = 0; i < 4; i++)
        #pragma unroll
        for (int j = 0; j < 4; j++)
          acc[i][j] = fmaf(a[i], b[j], acc[i][j]);
    }
    __syncthreads();
  }
  // C write
  #pragma unroll
  for (int i = 0; i < 4; i++){
    int r = row0 + ty * 4 + i;
    if (r < M){
      float4 v = make_float4(acc[i][0], acc[i][1], acc[i][2], acc[i][3]);
      *(float4*)&C[(size_t)r * N + col0 + tx * 4] = v;
    }
  }
  // fused att dots: es[r,head] = sum_c H[r, head*64+c]*asrc[head,c] (same for ed)
  float4 av = *(const float4*)&asrc[head * 64 + tx * 4];
  float4 dv = *(const float4*)&adst[head * 64 + tx * 4];
  #pragma unroll
  for (int i = 0; i < 4; i++){
    float ps = acc[i][0]*av.x + acc[i][1]*av.y + acc[i][2]*av.z + acc[i][3]*av.w;
    float pd = acc[i][0]*dv.x + acc[i][1]*dv.y + acc[i][2]*dv.z + acc[i][3]*dv.w;
    #pragma unroll
    for (int o = 1; o < 16; o <<= 1){
      ps += __shfl_xor(ps, o, 64);
      pd += __shfl_xor(pd, o, 64);
    }
    int r = row0 + ty * 4 + i;
    if (tx == 0 && r < M){
      es[(size_t)r * nh + head] = ps;
      ed[(size_t)r * nh + head] = pd;
    }
  }
}

// ---------------- layer-1 aggregation ----------------
// Fast path (deg<=64): edge-parallel softmax, shfl-broadcast accumulate,
// float4-per-lane channel layout (lane covers channels 4L..4L+3, head = L>>4).
__global__ __launch_bounds__(256) void agg1_kernel(const int* __restrict__ off,
                                                   const int* __restrict__ csr_src,
                                                   const float* __restrict__ H1,
                                                   const float* __restrict__ es,
                                                   const float* __restrict__ ed,
                                                   const float* __restrict__ b1,
                                                   const float* __restrict__ lng,
                                                   const float* __restrict__ lnb,
                                                   float* __restrict__ h1out, int n){
  int wid  = (blockIdx.x * blockDim.x + threadIdx.x) >> 6;
  int lane = threadIdx.x & 63;
  if (wid >= n) return;
  int s0  = off[wid];
  int deg = off[wid + 1] - s0;
  const float4 edv = *(const float4*)(ed + (size_t)wid * 4);

  float v0, v1, v2, v3;   // pre-LN values: lane's 4 channels (fast) or per-head ch (slow)

  if (deg <= 64){
    bool vld = lane < deg;
    int srcl = vld ? csr_src[s0 + lane] : 0;
    float4 e4 = vld ? *(const float4*)(es + (size_t)srcl * 4)
                    : make_float4(-1e30f, -1e30f, -1e30f, -1e30f);
    float e0 = vld ? lrelu(e4.x + edv.x) : -1e30f;
    float e1 = vld ? lrelu(e4.y + edv.y) : -1e30f;
    float e2 = vld ? lrelu(e4.z + edv.z) : -1e30f;
    float e3 = vld ? lrelu(e4.w + edv.w) : -1e30f;
    float m0 = wmaxr(e0), m1 = wmaxr(e1), m2 = wmaxr(e2), m3 = wmaxr(e3);
    float w0 = vld ? __expf(e0 - m0) : 0.f;
    float w1 = vld ? __expf(e1 - m1) : 0.f;
    float w2 = vld ? __expf(e2 - m2) : 0.f;
    float w3 = vld ? __expf(e3 - m3) : 0.f;
    w0 /= (wsum(w0) + 1e-16f);
    w1 /= (wsum(w1) + 1e-16f);
    w2 /= (wsum(w2) + 1e-16f);
    w3 /= (wsum(w3) + 1e-16f);

    int h = lane >> 4;   // this lane's head for its float4 channel group
    float ax = 0.f, ay = 0.f, az = 0.f, aw = 0.f;
    int t = 0;
    for (; t + 2 <= deg; t += 2){
      int  a0 = __shfl(srcl, t, 64),     a1 = __shfl(srcl, t + 1, 64);
      float q00 = __shfl(w0, t, 64), q01 = __shfl(w1, t, 64);
      float q02 = __shfl(w2, t, 64), q03 = __shfl(w3, t, 64);
      float q10 = __shfl(w0, t + 1, 64), q11 = __shfl(w1, t + 1, 64);
      float q12 = __shfl(w2, t + 1, 64), q13 = __shfl(w3, t + 1, 64);
      float ws0 = h == 0 ? q00 : h == 1 ? q01 : h == 2 ? q02 : q03;
      float ws1 = h == 0 ? q10 : h == 1 ? q11 : h == 2 ? q12 : q13;
      float4 hv0 = *(const float4*)(H1 + (size_t)a0 * 256 + lane * 4);
      float4 hv1 = *(const float4*)(H1 + (size_t)a1 * 256 + lane * 4);
      ax = fmaf(hv0.x, ws0, fmaf(hv1.x, ws1, ax));
      ay = fmaf(hv0.y, ws0, fmaf(hv1.y, ws1, ay));
      az = fmaf(hv0.z, ws0, fmaf(hv1.z, ws1, az));
      aw = fmaf(hv0.w, ws0, fmaf(hv1.w, ws1, aw));
    }
    for (; t < deg; t++){
      int a0 = __shfl(srcl, t, 64);
      float q0 = __shfl(w0, t, 64), q1 = __shfl(w1, t, 64);
      float q2 = __shfl(w2, t, 64), q3 = __shfl(w3, t, 64);
      float ws = h == 0 ? q0 : h == 1 ? q1 : h == 2 ? q2 : q3;
      float4 hv = *(const float4*)(H1 + (size_t)a0 * 256 + lane * 4);
      ax = fmaf(hv.x, ws, ax); ay = fmaf(hv.y, ws, ay);
      az = fmaf(hv.z, ws, az); aw = fmaf(hv.w, ws, aw);
    }
    float4 bb = *(const float4*)(b1 + lane * 4);
    v0 = eluf(ax + bb.x); v1 = eluf(ay + bb.y);
    v2 = eluf(az + bb.z); v3 = eluf(aw + bb.w);
    // LN over 256 then float4 store
    float mu = wsum(v0 + v1 + v2 + v3) * (1.f/256.f);
    float q  = (v0-mu)*(v0-mu) + (v1-mu)*(v1-mu) + (v2-mu)*(v2-mu) + (v3-mu)*(v3-mu);
    float rstd = rsqrtf(wsum(q) * (1.f/256.f) + 1e-5f);
    float4 g4 = *(const float4*)(lng + lane * 4);
    float4 bo = *(const float4*)(lnb + lane * 4);
    float4 o4 = make_float4((v0-mu)*rstd*g4.x + bo.x, (v1-mu)*rstd*g4.y + bo.y,
                            (v2-mu)*rstd*g4.z + bo.z, (v3-mu)*rstd*g4.w + bo.w);
    *(float4*)(h1out + (size_t)wid * 256 + lane * 4) = o4;
    return;
  }

  // slow path: deg > 64 (rare)
  float m0 = -1e30f, m1 = -1e30f, m2 = -1e30f, m3 = -1e30f;
  for (int j = lane; j < deg; j += 64){
    int src = csr_src[s0 + j];
    float4 e4 = *(const float4*)(es + (size_t)src * 4);
    m0 = fmaxf(m0, lrelu(e4.x + edv.x));
    m1 = fmaxf(m1, lrelu(e4.y + edv.y));
    m2 = fmaxf(m2, lrelu(e4.z + edv.z));
    m3 = fmaxf(m3, lrelu(e4.w + edv.w));
  }
  m0 = wmaxr(m0); m1 = wmaxr(m1); m2 = wmaxr(m2); m3 = wmaxr(m3);
  float acc0 = 0.f, acc1 = 0.f, acc2 = 0.f, acc3 = 0.f;
  float den0 = 0.f, den1 = 0.f, den2 = 0.f, den3 = 0.f;
  for (int j = 0; j < deg; j++){
    int src = csr_src[s0 + j];
    float4 e4 = *(const float4*)(es + (size_t)src * 4);
    float x0 = __expf(lrelu(e4.x + edv.x) - m0);
    float x1 = __expf(lrelu(e4.y + edv.y) - m1);
    float x2 = __expf(lrelu(e4.z + edv.z) - m2);
    float x3 = __expf(lrelu(e4.w + edv.w) - m3);
    den0 += x0; den1 += x1; den2 += x2; den3 += x3;
    const float* hp = H1 + (size_t)src * 256;
    acc0 = fmaf(hp[lane],       x0, acc0);
    acc1 = fmaf(hp[64 + lane],  x1, acc1);
    acc2 = fmaf(hp[128 + lane], x2, acc2);
    acc3 = fmaf(hp[192 + lane], x3, acc3);
  }
  v0 = eluf(acc0 / (den0 + 1e-16f) + b1[lane]);
  v1 = eluf(acc1 / (den1 + 1e-16f) + b1[64 + lane]);
  v2 = eluf(acc2 / (den2 + 1e-16f) + b1[128 + lane]);
  v3 = eluf(acc3 / (den3 + 1e-16f) + b1[192 + lane]);
  float mu = wsum(v0 + v1 + v2 + v3) * (1.f/256.f);
  float q  = (v0-mu)*(v0-mu) + (v1-mu)*(v1-mu) + (v2-mu)*(v2-mu) + (v3-mu)*(v3-mu);
  float rstd = rsqrtf(wsum(q) * (1.f/256.f) + 1e-5f);
  float* o = h1out + (size_t)wid * 256;
  o[lane]       = (v0-mu)*rstd*lng[lane]       + lnb[lane];
  o[64 + lane]  = (v1-mu)*rstd*lng[64 + lane]  + lnb[64 + lane];
  o[128 + lane] = (v2-mu)*rstd*lng[128 + lane] + lnb[128 + lane];
  o[192 + lane] = (v3-mu)*rstd*lng[192 + lane] + lnb[192 + lane];
}

// ---------------- layer-2 aggregation (1 head) ----------------
__global__ __launch_bounds__(256) void agg2_kernel(const int* __restrict__ off,
                                                   const int* __restrict__ csr_src,
                                                   const int* __restrict__ csr_eid,
                                                   const float* __restrict__ H2,
                                                   const float* __restrict__ es,
                                                   const float* __restrict__ ed,
                                                   const float* __restrict__ b2,
                                                   const float* __restrict__ lng,
                                                   const float* __restrict__ lnb,
                                                   float* __restrict__ h2out,
                                                   float* __restrict__ alpha_out, int n){
  int wid  = (blockIdx.x * blockDim.x + threadIdx.x) >> 6;
  int lane = threadIdx.x & 63;
  if (wid >= n) return;
  int s0  = off[wid];
  int deg = off[wid + 1] - s0;
  float edv = ed[wid];
  float acc = 0.f;

  if (deg <= 64){
    bool vld = lane < deg;
    int srcl = vld ? csr_src[s0 + lane] : 0;
    float el = vld ? lrelu(es[srcl] + edv) : -1e30f;
    float m  = wmaxr(el);
    float w  = vld ? __expf(el - m) : 0.f;
    float den = wsum(w) + 1e-16f;
    float wl = w / den;
    if (vld) alpha_out[csr_eid[s0 + lane]] = wl;
    int t = 0;
    for (; t + 4 <= deg; t += 4){
      int a0 = __shfl(srcl, t, 64),   a1 = __shfl(srcl, t+1, 64);
      int a2 = __shfl(srcl, t+2, 64), a3 = __shfl(srcl, t+3, 64);
      float q0 = __shfl(wl, t, 64),   q1 = __shfl(wl, t+1, 64);
      float q2 = __shfl(wl, t+2, 64), q3 = __shfl(wl, t+3, 64);
      float h0 = H2[(size_t)a0 * 64 + lane];
      float h1v = H2[(size_t)a1 * 64 + lane];
      float h2v = H2[(size_t)a2 * 64 + lane];
      float h3 = H2[(size_t)a3 * 64 + lane];
      acc = fmaf(h0, q0, acc); acc = fmaf(h1v, q1, acc);
      acc = fmaf(h2v, q2, acc); acc = fmaf(h3, q3, acc);
    }
    for (; t < deg; t++){
      int a0 = __shfl(srcl, t, 64);
      float q0 = __shfl(wl, t, 64);
      acc = fmaf(H2[(size_t)a0 * 64 + lane], q0, acc);
    }
  } else {
    float m = -1e30f;
    for (int j = lane; j < deg; j += 64){
      int src = csr_src[s0 + j];
      m = fmaxf(m, lrelu(es[src] + edv));
    }
    m = wmaxr(m);
    float den = 0.f;
    for (int j = lane; j < deg; j += 64){
      int src = csr_src[s0 + j];
      den += __expf(lrelu(es[src] + edv) - m);
    }
    den = wsum(den) + 1e-16f;
    for (int j = 0; j < deg; j++){
      int src = csr_src[s0 + j];
      float a = __expf(lrelu(es[src] + edv) - m) / den;
      if (lane == 0) alpha_out[csr_eid[s0 + j]] = a;
      acc = fmaf(H2[(size_t)src * 64 + lane], a, acc);
    }
  }
  float v  = acc + b2[lane];
  float mu = wsum(v) * (1.f/64.f);
  float d  = v - mu;
  float rstd = rsqrtf(wsum(d*d) * (1.f/64.f) + 1e-5f);
  h2out[(size_t)wid * 64 + lane] = d * rstd * lng[lane] + lnb[lane];
}

// ---------------- head: step/sentence MLP + dueling head ----------------
__global__ __launch_bounds__(64) void head_kernel(const float* __restrict__ semb,
                                                  const int* __restrict__ active,
                                                  const int* __restrict__ step,
                                                  const float* __restrict__ fc0w, const float* __restrict__ fc0b,
                                                  const float* __restrict__ fc1w, const float* __restrict__ fc1b,
                                                  const float* __restrict__ fc2w, const float* __restrict__ fc2b,
                                                  const float* __restrict__ fc3w, const float* __restrict__ fc3b,
                                                  const float* __restrict__ valw, const float* __restrict__ valb,
                                                  const float* __restrict__ advw, const float* __restrict__ advb,
                                                  const float* __restrict__ lnhg, const float* __restrict__ lnhb,
                                                  const float* __restrict__ lnfg, const float* __restrict__ lnfb,
                                                  const float* __restrict__ h2,
                                                  float* __restrict__ out){
  int t = threadIdx.x;  // one wave of 64
  __shared__ float sh[128];

  float sval = (float)(step[0] + 1) * 0.01f;
  float stepsv = ln64(fmaxf(fmaf(sval, fc0w[t], fc0b[t]), 0.f), lnhg, lnhb, t);

  float acc = fc1b[t];
  #pragma unroll 8
  for (int k = 0; k < 768; k++) acc = fmaf(semb[k], fc1w[k * 64 + t], acc);
  float sentv = ln64(fmaxf(acc, 0.f), lnhg, lnhb, t) + stepsv;
  sh[t] = sentv;
  __syncthreads();
  float acc2 = fc2b[t];
  #pragma unroll 8
  for (int k = 0; k < 64; k++) acc2 = fmaf(sh[k], fc2w[k * 64 + t], acc2);
  __syncthreads();
  float sent2 = ln64(fmaxf(acc2, 0.f), lnhg, lnhb, t);

  float a0 = h2[(size_t)active[0] * 64 + t];
  float a1 = sent2;
  float mu = wsum(a0 + a1) * (1.f/128.f);
  float q  = (a0-mu)*(a0-mu) + (a1-mu)*(a1-mu);
  float rstd = rsqrtf(wsum(q) * (1.f/128.f) + 1e-5f);
  float n0 = (a0-mu)*rstd*lnfg[t]      + lnfb[t];
  float n1 = (a1-mu)*rstd*lnfg[64 + t] + lnfb[64 + t];
  sh[t] = n0; sh[64 + t] = n1;
  __syncthreads();

  float acc3 = fc3b[t];
  #pragma unroll 8
  for (int k = 0; k < 128; k++) acc3 = fmaf(sh[k], fc3w[k * 64 + t], acc3);
  float a2v = ln64(fmaxf(acc3, 0.f), lnhg, lnhb, t);
  __syncthreads();
  sh[t] = a2v;
  __syncthreads();

  float val = wsum(a2v * valw[t]) + valb[0];
  float advv = 0.f;
  if (t < 32){
    advv = advb[t];
    #pragma unroll 8
    for (int k = 0; k < 64; k++) advv = fmaf(sh[k], advw[k * 32 + t], advv);
  }
  float am = wsum(t < 32 ? advv : 0.f) * (1.f/32.f);
  if (t < 32) out[t] = tanhf(val + advv - am);
}

extern "C" void kernel_launch(void* const* d_in, const int* in_sizes, int n_in,
                              void* d_out, int out_size, void* d_ws, size_t ws_size,
                              hipStream_t stream) {
  const float* x     = (const float*)d_in[0];
  const int*   ei    = (const int*)  d_in[1];
  const float* semb  = (const float*)d_in[2];
  const int*   act   = (const int*)  d_in[3];
  const int*   step  = (const int*)  d_in[4];
  const float* W1    = (const float*)d_in[5];
  const float* as1   = (const float*)d_in[6];
  const float* ad1   = (const float*)d_in[7];
  const float* b1    = (const float*)d_in[8];
  const float* W2    = (const float*)d_in[9];
  const float* as2   = (const float*)d_in[10];
  const float* ad2   = (const float*)d_in[11];
  const float* b2    = (const float*)d_in[12];
  const float* fc0w  = (const float*)d_in[13];
  const float* fc0b  = (const float*)d_in[14];
  const float* fc1w  = (const float*)d_in[15];
  const float* fc1b  = (const float*)d_in[16];
  const float* fc2w  = (const float*)d_in[17];
  const float* fc2b  = (const float*)d_in[18];
  const float* fc3w  = (const float*)d_in[19];
  const float* fc3b  = (const float*)d_in[20];
  const float* valw  = (const float*)d_in[21];
  const float* valb  = (const float*)d_in[22];
  const float* advw  = (const float*)d_in[23];
  const float* advb  = (const float*)d_in[24];
  const float* lnhg  = (const float*)d_in[25];
  const float* lnhb  = (const float*)d_in[26];
  const float* lnfg  = (const float*)d_in[27];
  const float* lnfb  = (const float*)d_in[28];
  const float* lnag  = (const float*)d_in[29];
  const float* lnab  = (const float*)d_in[30];

  char* ws = (char*)d_ws;
  size_t o = 0;
  auto alloc = [&](size_t bytes) -> void* {
    o = (o + 255) & ~(size_t)255;
    void* p = ws + o;
    o += bytes;
    return p;
  };
  int*   deg     = (int*)  alloc((size_t)(NN + 1) * 4);
  int*   off     = (int*)  alloc((size_t)(NN + 1) * 4);
  int*   cur     = (int*)  alloc((size_t)NN * 4);
  int*   csr_src = (int*)  alloc((size_t)ET * 4);
  int*   csr_eid = (int*)  alloc((size_t)ET * 4);
  float* H1      = (float*)alloc((size_t)NN * 256 * 4);
  float* h1      = (float*)alloc((size_t)NN * 256 * 4);
  float* es1     = (float*)alloc((size_t)NN * 16);
  float* ed1     = (float*)alloc((size_t)NN * 16);
  float* H2  = H1;    // aliases; lifetimes don't overlap
  float* es2 = es1;
  float* ed2 = ed1;

  float* logits    = (float*)d_out;
  float* h2out     = (float*)d_out + 32;
  float* alpha_out = (float*)d_out + 32 + (size_t)NN * 64;

  // CSR build
  hipMemsetAsync(deg, 0, (size_t)NN * 4, stream);
  degree_kernel<<<(ET + 255) / 256, 256, 0, stream>>>(ei, deg);
  scan_kernel<<<1, 1024, 0, stream>>>(deg, off, cur, NN);
  fill_csr<<<(ET + 255) / 256, 256, 0, stream>>>(ei, cur, csr_src, csr_eid);

  // layer 1 (att dots fused into gemm epilogue)
  gemm_att<<<dim3(4, (NN + 63) / 64), 256, 0, stream>>>(x, W1, H1, NN, 256, 128,
                                                        as1, ad1, es1, ed1, 4);
  agg1_kernel<<<NN / 4, 256, 0, stream>>>(off, csr_src, H1, es1, ed1, b1, lnag, lnab, h1, NN);

  // layer 2
  gemm_att<<<dim3(1, (NN + 63) / 64), 256, 0, stream>>>(h1, W2, H2, NN, 64, 256,
                                                        as2, ad2, es2, ed2, 1);
  agg2_kernel<<<NN / 4, 256, 0, stream>>>(off, csr_src, csr_eid, H2, es2, ed2, b2,
                                          lnhg, lnhb, h2out, alpha_out, NN);

  // head
  head_kernel<<<1, 64, 0, stream>>>(semb, act, step,
                                    fc0w, fc0b, fc1w, fc1b, fc2w, fc2b, fc3w, fc3b,
                                    valw, valb, advw, advb,
                                    lnhg, lnhb, lnfg, lnfb,
                                    h2out, logits);
}

// Round 3
// 499.039 us; speedup vs baseline: 1.2922x; 1.0906x over previous
//
#include <hip/hip_runtime.h>
#include <cstdint>
#include <cstddef>

#define DEV __device__ __forceinline__

static constexpr int NN  = 50000;
static constexpr int EE  = 600000;
static constexpr int ET  = 650000;   // EE + NN self loops

DEV float wsum(float v){
  #pragma unroll
  for (int o = 32; o > 0; o >>= 1) v += __shfl_xor(v, o, 64);
  return v;
}
DEV float wmaxr(float v){
  #pragma unroll
  for (int o = 32; o > 0; o >>= 1) v = fmaxf(v, __shfl_xor(v, o, 64));
  return v;
}
DEV float lrelu(float x){ return x > 0.f ? x : 0.2f * x; }
DEV float eluf(float x){ return x > 0.f ? x : expm1f(x); }
DEV float ln64(float v, const float* g, const float* b, int lane){
  float mu  = wsum(v) * (1.f/64.f);
  float d   = v - mu;
  float var = wsum(d*d) * (1.f/64.f);
  return d * rsqrtf(var + 1e-5f) * g[lane] + b[lane];
}
// f32 -> bf16 (RNE) as raw ushort bits
DEV unsigned int bf16u(float f){
  unsigned int u = __float_as_uint(f);
  return (u + 0x7fffu + ((u >> 16) & 1u)) >> 16;
}
DEV float bfl(unsigned int lo16){ return __uint_as_float(lo16 << 16); }

// ---------------- CSR build ----------------
__global__ void degree_kernel(const int* __restrict__ ei, int* __restrict__ deg){
  int e = blockIdx.x * blockDim.x + threadIdx.x;
  if (e >= ET) return;
  int dst = (e < EE) ? ei[EE + e] : (e - EE);
  atomicAdd(&deg[dst], 1);
}

__global__ __launch_bounds__(1024) void scan_kernel(const int* __restrict__ deg,
                                                    int* __restrict__ off,
                                                    int* __restrict__ cur, int n){
  __shared__ int wsh[16];
  __shared__ int s_run;
  int tid = threadIdx.x, lane = tid & 63, w = tid >> 6;
  if (tid == 0) s_run = 0;
  __syncthreads();
  const int PER = 8, CH = 1024 * PER;
  for (int base = 0; base < n; base += CH){
    int v[PER]; int s = 0;
    int i0 = base + tid * PER;
    #pragma unroll
    for (int p = 0; p < PER; p++){ int i = i0 + p; v[p] = (i < n) ? deg[i] : 0; s += v[p]; }
    int sc = s;
    #pragma unroll
    for (int d = 1; d < 64; d <<= 1){ int t = __shfl_up(sc, d, 64); if (lane >= d) sc += t; }
    if (lane == 63) wsh[w] = sc;
    __syncthreads();
    int run = s_run;
    int woff = 0;
    for (int k = 0; k < w; k++) woff += wsh[k];
    int excl = run + woff + sc - s;
    #pragma unroll
    for (int p = 0; p < PER; p++){
      int i = i0 + p;
      if (i < n){ off[i] = excl; cur[i] = excl; }
      excl += v[p];
    }
    __syncthreads();
    if (tid == 0){ int tot = 0; for (int k = 0; k < 16; k++) tot += wsh[k]; s_run = run + tot; }
    __syncthreads();
  }
  if (threadIdx.x == 0) off[n] = s_run;
}

__global__ void fill_csr(const int* __restrict__ ei, int* __restrict__ cur,
                         int* __restrict__ csr_src, int* __restrict__ csr_eid){
  int e = blockIdx.x * blockDim.x + threadIdx.x;
  if (e >= ET) return;
  int src, dst;
  if (e < EE){ src = ei[e]; dst = ei[EE + e]; } else { src = dst = e - EE; }
  int pos = atomicAdd(&cur[dst], 1);
  csr_src[pos] = src;
  csr_eid[pos] = e;
}

// ---------------- f32 tiled GEMM, bf16 C-store, fused attention-dot epilogue ----------------
// C[M,N] = A[M,K] @ B[K,N]; BM=64,BN=64,BK=32; 256 thr, 4x4/thread.
// C is stored as bf16 (ushort). es/ed computed from the f32 accumulators.
__global__ __launch_bounds__(256) void gemm_att(const float* __restrict__ A,
                                                const float* __restrict__ B,
                                                unsigned short* __restrict__ Cb,
                                                int M, int N, int K,
                                                const float* __restrict__ asrc,
                                                const float* __restrict__ adst,
                                                float* __restrict__ es,
                                                float* __restrict__ ed, int nh){
  constexpr int BM = 64, BN = 64, BK = 32;
  __shared__ float As[BK][BM + 1];
  __shared__ float Bs[BK][BN];
  int tid = threadIdx.x;
  int tx = tid & 15;        // 16
  int ty = tid >> 4;        // 16
  int row0 = blockIdx.y * BM;
  int col0 = blockIdx.x * BN;
  int head = blockIdx.x;
  float acc[4][4] = {};
  for (int k0 = 0; k0 < K; k0 += BK){
    #pragma unroll
    for (int l = 0; l < 2; l++){
      int i  = tid + l * 256;
      int r  = i >> 3;
      int c4 = (i & 7) * 4;
      float4 v = make_float4(0.f, 0.f, 0.f, 0.f);
      if (row0 + r < M)
        v = *(const float4*)&A[(size_t)(row0 + r) * K + k0 + c4];
      As[c4 + 0][r] = v.x; As[c4 + 1][r] = v.y; As[c4 + 2][r] = v.z; As[c4 + 3][r] = v.w;
    }
    #pragma unroll
    for (int l = 0; l < 2; l++){
      int i  = tid + l * 256;
      int r  = i >> 4;
      int c4 = (i & 15) * 4;
      float4 v = *(const float4*)&B[(size_t)(k0 + r) * N + col0 + c4];
      *(float4*)&Bs[r][c4] = v;
    }
    __syncthreads();
    #pragma unroll
    for (int kk = 0; kk < BK; kk++){
      float a[4];
      #pragma unroll
      for (int i = 0; i < 4; i++) a[i] = As[kk][ty * 4 + i];
      float4 bv = *(const float4*)&Bs[kk][tx * 4];
      float b[4] = {bv.x, bv.y, bv.z, bv.w};
      #pragma unroll
      for (int i = 0; i < 4; i++)
        #pragma unroll
        for (int j = 0; j < 4; j++)
          acc[i][j] = fmaf(a[i], b[j], acc[i][j]);
    }
    __syncthreads();
  }
  // bf16 C write (8 B per row-chunk)
  #pragma unroll
  for (int i = 0; i < 4; i++){
    int r = row0 + ty * 4 + i;
    if (r < M){
      uint2 p;
      p.x = bf16u(acc[i][0]) | (bf16u(acc[i][1]) << 16);
      p.y = bf16u(acc[i][2]) | (bf16u(acc[i][3]) << 16);
      *(uint2*)&Cb[(size_t)r * N + col0 + tx * 4] = p;
    }
  }
  // fused att dots: es[r,head] = sum_c H[r, head*64+c]*asrc[head,c] (same for ed)
  float4 av = *(const float4*)&asrc[head * 64 + tx * 4];
  float4 dv = *(const float4*)&adst[head * 64 + tx * 4];
  #pragma unroll
  for (int i = 0; i < 4; i++){
    float ps = acc[i][0]*av.x + acc[i][1]*av.y + acc[i][2]*av.z + acc[i][3]*av.w;
    float pd = acc[i][0]*dv.x + acc[i][1]*dv.y + acc[i][2]*dv.z + acc[i][3]*dv.w;
    #pragma unroll
    for (int o = 1; o < 16; o <<= 1){
      ps += __shfl_xor(ps, o, 64);
      pd += __shfl_xor(pd, o, 64);
    }
    int r = row0 + ty * 4 + i;
    if (tx == 0 && r < M){
      es[(size_t)r * nh + head] = ps;
      ed[(size_t)r * nh + head] = pd;
    }
  }
}

// ---------------- layer-1 aggregation (bf16 H1 gather) ----------------
// Fast path (deg<=64): edge-parallel softmax; weights+srcs staged in LDS for
// broadcast; lane covers 4 channels (uint2 = 4 bf16), head = lane>>4.
__global__ __launch_bounds__(256) void agg1_kernel(const int* __restrict__ off,
                                                   const int* __restrict__ csr_src,
                                                   const unsigned short* __restrict__ H1b,
                                                   const float* __restrict__ es,
                                                   const float* __restrict__ ed,
                                                   const float* __restrict__ b1,
                                                   const float* __restrict__ lng,
                                                   const float* __restrict__ lnb,
                                                   float* __restrict__ h1out, int n){
  __shared__ float wsh4[4][64][4];
  __shared__ int   ssh[4][64];
  int wv   = threadIdx.x >> 6;
  int wid  = (blockIdx.x * blockDim.x + threadIdx.x) >> 6;
  int lane = threadIdx.x & 63;
  if (wid >= n) return;
  int s0  = off[wid];
  int deg = off[wid + 1] - s0;
  const float4 edv = *(const float4*)(ed + (size_t)wid * 4);

  float v0, v1, v2, v3;

  if (deg <= 64){
    bool vld = lane < deg;
    int srcl = vld ? csr_src[s0 + lane] : 0;
    float4 e4 = vld ? *(const float4*)(es + (size_t)srcl * 4)
                    : make_float4(-1e30f, -1e30f, -1e30f, -1e30f);
    float e0 = vld ? lrelu(e4.x + edv.x) : -1e30f;
    float e1 = vld ? lrelu(e4.y + edv.y) : -1e30f;
    float e2 = vld ? lrelu(e4.z + edv.z) : -1e30f;
    float e3 = vld ? lrelu(e4.w + edv.w) : -1e30f;
    float m0 = wmaxr(e0), m1 = wmaxr(e1), m2 = wmaxr(e2), m3 = wmaxr(e3);
    float w0 = vld ? __expf(e0 - m0) : 0.f;
    float w1 = vld ? __expf(e1 - m1) : 0.f;
    float w2 = vld ? __expf(e2 - m2) : 0.f;
    float w3 = vld ? __expf(e3 - m3) : 0.f;
    w0 /= (wsum(w0) + 1e-16f);
    w1 /= (wsum(w1) + 1e-16f);
    w2 /= (wsum(w2) + 1e-16f);
    w3 /= (wsum(w3) + 1e-16f);
    ssh[wv][lane] = srcl;
    *(float4*)&wsh4[wv][lane][0] = make_float4(w0, w1, w2, w3);
    __builtin_amdgcn_wave_barrier();   // same-wave DS in-order; pin compiler order

    int h = lane >> 4;
    float ax = 0.f, ay = 0.f, az = 0.f, aw = 0.f;
    int t = 0;
    for (; t + 4 <= deg; t += 4){
      int a0 = ssh[wv][t],     a1 = ssh[wv][t + 1];
      int a2 = ssh[wv][t + 2], a3 = ssh[wv][t + 3];
      float q0 = wsh4[wv][t][h],     q1 = wsh4[wv][t + 1][h];
      float q2 = wsh4[wv][t + 2][h], q3 = wsh4[wv][t + 3][h];
      uint2 g0 = *(const uint2*)(H1b + (size_t)a0 * 256 + lane * 4);
      uint2 g1 = *(const uint2*)(H1b + (size_t)a1 * 256 + lane * 4);
      uint2 g2 = *(const uint2*)(H1b + (size_t)a2 * 256 + lane * 4);
      uint2 g3 = *(const uint2*)(H1b + (size_t)a3 * 256 + lane * 4);
      ax = fmaf(__uint_as_float(g0.x << 16),        q0, ax);
      ay = fmaf(__uint_as_float(g0.x & 0xffff0000u), q0, ay);
      az = fmaf(__uint_as_float(g0.y << 16),        q0, az);
      aw = fmaf(__uint_as_float(g0.y & 0xffff0000u), q0, aw);
      ax = fmaf(__uint_as_float(g1.x << 16),        q1, ax);
      ay = fmaf(__uint_as_float(g1.x & 0xffff0000u), q1, ay);
      az = fmaf(__uint_as_float(g1.y << 16),        q1, az);
      aw = fmaf(__uint_as_float(g1.y & 0xffff0000u), q1, aw);
      ax = fmaf(__uint_as_float(g2.x << 16),        q2, ax);
      ay = fmaf(__uint_as_float(g2.x & 0xffff0000u), q2, ay);
      az = fmaf(__uint_as_float(g2.y << 16),        q2, az);
      aw = fmaf(__uint_as_float(g2.y & 0xffff0000u), q2, aw);
      ax = fmaf(__uint_as_float(g3.x << 16),        q3, ax);
      ay = fmaf(__uint_as_float(g3.x & 0xffff0000u), q3, ay);
      az = fmaf(__uint_as_float(g3.y << 16),        q3, az);
      aw = fmaf(__uint_as_float(g3.y & 0xffff0000u), q3, aw);
    }
    for (; t < deg; t++){
      int a0 = ssh[wv][t];
      float q0 = wsh4[wv][t][h];
      uint2 g0 = *(const uint2*)(H1b + (size_t)a0 * 256 + lane * 4);
      ax = fmaf(__uint_as_float(g0.x << 16),        q0, ax);
      ay = fmaf(__uint_as_float(g0.x & 0xffff0000u), q0, ay);
      az = fmaf(__uint_as_float(g0.y << 16),        q0, az);
      aw = fmaf(__uint_as_float(g0.y & 0xffff0000u), q0, aw);
    }
    float4 bb = *(const float4*)(b1 + lane * 4);
    v0 = eluf(ax + bb.x); v1 = eluf(ay + bb.y);
    v2 = eluf(az + bb.z); v3 = eluf(aw + bb.w);
    float mu = wsum(v0 + v1 + v2 + v3) * (1.f/256.f);
    float q  = (v0-mu)*(v0-mu) + (v1-mu)*(v1-mu) + (v2-mu)*(v2-mu) + (v3-mu)*(v3-mu);
    float rstd = rsqrtf(wsum(q) * (1.f/256.f) + 1e-5f);
    float4 g4 = *(const float4*)(lng + lane * 4);
    float4 bo = *(const float4*)(lnb + lane * 4);
    float4 o4 = make_float4((v0-mu)*rstd*g4.x + bo.x, (v1-mu)*rstd*g4.y + bo.y,
                            (v2-mu)*rstd*g4.z + bo.z, (v3-mu)*rstd*g4.w + bo.w);
    *(float4*)(h1out + (size_t)wid * 256 + lane * 4) = o4;
    return;
  }

  // slow path: deg > 64 (rare); channel layout: lane = channel within head
  float m0 = -1e30f, m1 = -1e30f, m2 = -1e30f, m3 = -1e30f;
  for (int j = lane; j < deg; j += 64){
    int src = csr_src[s0 + j];
    float4 e4 = *(const float4*)(es + (size_t)src * 4);
    m0 = fmaxf(m0, lrelu(e4.x + edv.x));
    m1 = fmaxf(m1, lrelu(e4.y + edv.y));
    m2 = fmaxf(m2, lrelu(e4.z + edv.z));
    m3 = fmaxf(m3, lrelu(e4.w + edv.w));
  }
  m0 = wmaxr(m0); m1 = wmaxr(m1); m2 = wmaxr(m2); m3 = wmaxr(m3);
  float acc0 = 0.f, acc1 = 0.f, acc2 = 0.f, acc3 = 0.f;
  float den0 = 0.f, den1 = 0.f, den2 = 0.f, den3 = 0.f;
  for (int j = 0; j < deg; j++){
    int src = csr_src[s0 + j];
    float4 e4 = *(const float4*)(es + (size_t)src * 4);
    float x0 = __expf(lrelu(e4.x + edv.x) - m0);
    float x1 = __expf(lrelu(e4.y + edv.y) - m1);
    float x2 = __expf(lrelu(e4.z + edv.z) - m2);
    float x3 = __expf(lrelu(e4.w + edv.w) - m3);
    den0 += x0; den1 += x1; den2 += x2; den3 += x3;
    const unsigned short* hp = H1b + (size_t)src * 256;
    acc0 = fmaf(bfl(hp[lane]),       x0, acc0);
    acc1 = fmaf(bfl(hp[64 + lane]),  x1, acc1);
    acc2 = fmaf(bfl(hp[128 + lane]), x2, acc2);
    acc3 = fmaf(bfl(hp[192 + lane]), x3, acc3);
  }
  v0 = eluf(acc0 / (den0 + 1e-16f) + b1[lane]);
  v1 = eluf(acc1 / (den1 + 1e-16f) + b1[64 + lane]);
  v2 = eluf(acc2 / (den2 + 1e-16f) + b1[128 + lane]);
  v3 = eluf(acc3 / (den3 + 1e-16f) + b1[192 + lane]);
  float mu = wsum(v0 + v1 + v2 + v3) * (1.f/256.f);
  float q  = (v0-mu)*(v0-mu) + (v1-mu)*(v1-mu) + (v2-mu)*(v2-mu) + (v3-mu)*(v3-mu);
  float rstd = rsqrtf(wsum(q) * (1.f/256.f) + 1e-5f);
  float* o = h1out + (size_t)wid * 256;
  o[lane]       = (v0-mu)*rstd*lng[lane]       + lnb[lane];
  o[64 + lane]  = (v1-mu)*rstd*lng[64 + lane]  + lnb[64 + lane];
  o[128 + lane] = (v2-mu)*rstd*lng[128 + lane] + lnb[128 + lane];
  o[192 + lane] = (v3-mu)*rstd*lng[192 + lane] + lnb[192 + lane];
}

// ---------------- layer-2 aggregation (1 head, bf16 H2 gather) ----------------
__global__ __launch_bounds__(256) void agg2_kernel(const int* __restrict__ off,
                                                   const int* __restrict__ csr_src,
                                                   const int* __restrict__ csr_eid,
                                                   const unsigned short* __restrict__ H2b,
                                                   const float* __restrict__ es,
                                                   const float* __restrict__ ed,
                                                   const float* __restrict__ b2,
                                                   const float* __restrict__ lng,
                                                   const float* __restrict__ lnb,
                                                   float* __restrict__ h2out,
                                                   float* __restrict__ alpha_out, int n){
  int wid  = (blockIdx.x * blockDim.x + threadIdx.x) >> 6;
  int lane = threadIdx.x & 63;
  if (wid >= n) return;
  int s0  = off[wid];
  int deg = off[wid + 1] - s0;
  float edv = ed[wid];
  float acc = 0.f;

  if (deg <= 64){
    bool vld = lane < deg;
    int srcl = vld ? csr_src[s0 + lane] : 0;
    float el = vld ? lrelu(es[srcl] + edv) : -1e30f;
    float m  = wmaxr(el);
    float w  = vld ? __expf(el - m) : 0.f;
    float den = wsum(w) + 1e-16f;
    float wl = w / den;
    if (vld) alpha_out[csr_eid[s0 + lane]] = wl;
    int t = 0;
    for (; t + 4 <= deg; t += 4){
      int a0 = __shfl(srcl, t, 64),   a1 = __shfl(srcl, t+1, 64);
      int a2 = __shfl(srcl, t+2, 64), a3 = __shfl(srcl, t+3, 64);
      float q0 = __shfl(wl, t, 64),   q1 = __shfl(wl, t+1, 64);
      float q2 = __shfl(wl, t+2, 64), q3 = __shfl(wl, t+3, 64);
      float h0 = bfl(H2b[(size_t)a0 * 64 + lane]);
      float h1v = bfl(H2b[(size_t)a1 * 64 + lane]);
      float h2v = bfl(H2b[(size_t)a2 * 64 + lane]);
      float h3 = bfl(H2b[(size_t)a3 * 64 + lane]);
      acc = fmaf(h0, q0, acc); acc = fmaf(h1v, q1, acc);
      acc = fmaf(h2v, q2, acc); acc = fmaf(h3, q3, acc);
    }
    for (; t < deg; t++){
      int a0 = __shfl(srcl, t, 64);
      float q0 = __shfl(wl, t, 64);
      acc = fmaf(bfl(H2b[(size_t)a0 * 64 + lane]), q0, acc);
    }
  } else {
    float m = -1e30f;
    for (int j = lane; j < deg; j += 64){
      int src = csr_src[s0 + j];
      m = fmaxf(m, lrelu(es[src] + edv));
    }
    m = wmaxr(m);
    float den = 0.f;
    for (int j = lane; j < deg; j += 64){
      int src = csr_src[s0 + j];
      den += __expf(lrelu(es[src] + edv) - m);
    }
    den = wsum(den) + 1e-16f;
    for (int j = 0; j < deg; j++){
      int src = csr_src[s0 + j];
      float a = __expf(lrelu(es[src] + edv) - m) / den;
      if (lane == 0) alpha_out[csr_eid[s0 + j]] = a;
      acc = fmaf(bfl(H2b[(size_t)src * 64 + lane]), a, acc);
    }
  }
  float v  = acc + b2[lane];
  float mu = wsum(v) * (1.f/64.f);
  float d  = v - mu;
  float rstd = rsqrtf(wsum(d*d) * (1.f/64.f) + 1e-5f);
  h2out[(size_t)wid * 64 + lane] = d * rstd * lng[lane] + lnb[lane];
}

// ---------------- head: step/sentence MLP + dueling head ----------------
__global__ __launch_bounds__(64) void head_kernel(const float* __restrict__ semb,
                                                  const int* __restrict__ active,
                                                  const int* __restrict__ step,
                                                  const float* __restrict__ fc0w, const float* __restrict__ fc0b,
                                                  const float* __restrict__ fc1w, const float* __restrict__ fc1b,
                                                  const float* __restrict__ fc2w, const float* __restrict__ fc2b,
                                                  const float* __restrict__ fc3w, const float* __restrict__ fc3b,
                                                  const float* __restrict__ valw, const float* __restrict__ valb,
                                                  const float* __restrict__ advw, const float* __restrict__ advb,
                                                  const float* __restrict__ lnhg, const float* __restrict__ lnhb,
                                                  const float* __restrict__ lnfg, const float* __restrict__ lnfb,
                                                  const float* __restrict__ h2,
                                                  float* __restrict__ out){
  int t = threadIdx.x;  // one wave of 64
  __shared__ float sh[128];

  float sval = (float)(step[0] + 1) * 0.01f;
  float stepsv = ln64(fmaxf(fmaf(sval, fc0w[t], fc0b[t]), 0.f), lnhg, lnhb, t);

  float acc = fc1b[t];
  #pragma unroll 8
  for (int k = 0; k < 768; k++) acc = fmaf(semb[k], fc1w[k * 64 + t], acc);
  float sentv = ln64(fmaxf(acc, 0.f), lnhg, lnhb, t) + stepsv;
  sh[t] = sentv;
  __syncthreads();
  float acc2 = fc2b[t];
  #pragma unroll 8
  for (int k = 0; k < 64; k++) acc2 = fmaf(sh[k], fc2w[k * 64 + t], acc2);
  __syncthreads();
  float sent2 = ln64(fmaxf(acc2, 0.f), lnhg, lnhb, t);

  float a0 = h2[(size_t)active[0] * 64 + t];
  float a1 = sent2;
  float mu = wsum(a0 + a1) * (1.f/128.f);
  float q  = (a0-mu)*(a0-mu) + (a1-mu)*(a1-mu);
  float rstd = rsqrtf(wsum(q) * (1.f/128.f) + 1e-5f);
  float n0 = (a0-mu)*rstd*lnfg[t]      + lnfb[t];
  float n1 = (a1-mu)*rstd*lnfg[64 + t] + lnfb[64 + t];
  sh[t] = n0; sh[64 + t] = n1;
  __syncthreads();

  float acc3 = fc3b[t];
  #pragma unroll 8
  for (int k = 0; k < 128; k++) acc3 = fmaf(sh[k], fc3w[k * 64 + t], acc3);
  float a2v = ln64(fmaxf(acc3, 0.f), lnhg, lnhb, t);
  __syncthreads();
  sh[t] = a2v;
  __syncthreads();

  float val = wsum(a2v * valw[t]) + valb[0];
  float advv = 0.f;
  if (t < 32){
    advv = advb[t];
    #pragma unroll 8
    for (int k = 0; k < 64; k++) advv = fmaf(sh[k], advw[k * 32 + t], advv);
  }
  float am = wsum(t < 32 ? advv : 0.f) * (1.f/32.f);
  if (t < 32) out[t] = tanhf(val + advv - am);
}

extern "C" void kernel_launch(void* const* d_in, const int* in_sizes, int n_in,
                              void* d_out, int out_size, void* d_ws, size_t ws_size,
                              hipStream_t stream) {
  const float* x     = (const float*)d_in[0];
  const int*   ei    = (const int*)  d_in[1];
  const float* semb  = (const float*)d_in[2];
  const int*   act   = (const int*)  d_in[3];
  const int*   step  = (const int*)  d_in[4];
  const float* W1    = (const float*)d_in[5];
  const float* as1   = (const float*)d_in[6];
  const float* ad1   = (const float*)d_in[7];
  const float* b1    = (const float*)d_in[8];
  const float* W2    = (const float*)d_in[9];
  const float* as2   = (const float*)d_in[10];
  const float* ad2   = (const float*)d_in[11];
  const float* b2    = (const float*)d_in[12];
  const float* fc0w  = (const float*)d_in[13];
  const float* fc0b  = (const float*)d_in[14];
  const float* fc1w  = (const float*)d_in[15];
  const float* fc1b  = (const float*)d_in[16];
  const float* fc2w  = (const float*)d_in[17];
  const float* fc2b  = (const float*)d_in[18];
  const float* fc3w  = (const float*)d_in[19];
  const float* fc3b  = (const float*)d_in[20];
  const float* valw  = (const float*)d_in[21];
  const float* valb  = (const float*)d_in[22];
  const float* advw  = (const float*)d_in[23];
  const float* advb  = (const float*)d_in[24];
  const float* lnhg  = (const float*)d_in[25];
  const float* lnhb  = (const float*)d_in[26];
  const float* lnfg  = (const float*)d_in[27];
  const float* lnfb  = (const float*)d_in[28];
  const float* lnag  = (const float*)d_in[29];
  const float* lnab  = (const float*)d_in[30];

  char* ws = (char*)d_ws;
  size_t o = 0;
  auto alloc = [&](size_t bytes) -> void* {
    o = (o + 255) & ~(size_t)255;
    void* p = ws + o;
    o += bytes;
    return p;
  };
  int*   deg     = (int*)  alloc((size_t)(NN + 1) * 4);
  int*   off     = (int*)  alloc((size_t)(NN + 1) * 4);
  int*   cur     = (int*)  alloc((size_t)NN * 4);
  int*   csr_src = (int*)  alloc((size_t)ET * 4);
  int*   csr_eid = (int*)  alloc((size_t)ET * 4);
  unsigned short* H1b = (unsigned short*)alloc((size_t)NN * 256 * 2);  // bf16 H1
  float* h1      = (float*)alloc((size_t)NN * 256 * 4);
  float* es1     = (float*)alloc((size_t)NN * 16);
  float* ed1     = (float*)alloc((size_t)NN * 16);
  unsigned short* H2b = H1b;   // aliases; lifetimes don't overlap
  float* es2 = es1;
  float* ed2 = ed1;

  float* logits    = (float*)d_out;
  float* h2out     = (float*)d_out + 32;
  float* alpha_out = (float*)d_out + 32 + (size_t)NN * 64;

  // CSR build
  hipMemsetAsync(deg, 0, (size_t)NN * 4, stream);
  degree_kernel<<<(ET + 255) / 256, 256, 0, stream>>>(ei, deg);
  scan_kernel<<<1, 1024, 0, stream>>>(deg, off, cur, NN);
  fill_csr<<<(ET + 255) / 256, 256, 0, stream>>>(ei, cur, csr_src, csr_eid);

  // layer 1 (att dots fused into gemm epilogue; C stored bf16)
  gemm_att<<<dim3(4, (NN + 63) / 64), 256, 0, stream>>>(x, W1, H1b, NN, 256, 128,
                                                        as1, ad1, es1, ed1, 4);
  agg1_kernel<<<NN / 4, 256, 0, stream>>>(off, csr_src, H1b, es1, ed1, b1, lnag, lnab, h1, NN);

  // layer 2
  gemm_att<<<dim3(1, (NN + 63) / 64), 256, 0, stream>>>(h1, W2, H2b, NN, 64, 256,
                                                        as2, ad2, es2, ed2, 1);
  agg2_kernel<<<NN / 4, 256, 0, stream>>>(off, csr_src, csr_eid, H2b, es2, ed2, b2,
                                          lnhg, lnhb, h2out, alpha_out, NN);

  // head
  head_kernel<<<1, 64, 0, stream>>>(semb, act, step,
                                    fc0w, fc0b, fc1w, fc1b, fc2w, fc2b, fc3w, fc3b,
                                    valw, valb, advw, advb,
                                    lnhg, lnhb, lnfg, lnfb,
                                    h2out, logits);
}

// Round 4
// 435.034 us; speedup vs baseline: 1.4824x; 1.1471x over previous
//
#include <hip/hip_runtime.h>
#include <cstdint>
#include <cstddef>

#define DEV __device__ __forceinline__

static constexpr int NN  = 50000;
static constexpr int EE  = 600000;
static constexpr int ET  = 650000;   // EE + NN self loops
static constexpr int SCAN_CHUNK = 1024;                 // 256 threads x 4
static constexpr int SCAN_NB = (NN + SCAN_CHUNK - 1) / SCAN_CHUNK;   // 49

DEV float wsum(float v){
  #pragma unroll
  for (int o = 32; o > 0; o >>= 1) v += __shfl_xor(v, o, 64);
  return v;
}
DEV float wmaxr(float v){
  #pragma unroll
  for (int o = 32; o > 0; o >>= 1) v = fmaxf(v, __shfl_xor(v, o, 64));
  return v;
}
DEV float lrelu(float x){ return x > 0.f ? x : 0.2f * x; }
DEV float eluf(float x){ return x > 0.f ? x : expm1f(x); }
DEV float ln64(float v, const float* g, const float* b, int lane){
  float mu  = wsum(v) * (1.f/64.f);
  float d   = v - mu;
  float var = wsum(d*d) * (1.f/64.f);
  return d * rsqrtf(var + 1e-5f) * g[lane] + b[lane];
}
// f32 -> bf16 (RNE) as raw ushort bits
DEV unsigned int bf16u(float f){
  unsigned int u = __float_as_uint(f);
  return (u + 0x7fffu + ((u >> 16) & 1u)) >> 16;
}
DEV float bfl(unsigned int lo16){ return __uint_as_float(lo16 << 16); }

// ---------------- CSR build ----------------
__global__ void degree_kernel(const int* __restrict__ ei, int* __restrict__ deg){
  int e = blockIdx.x * blockDim.x + threadIdx.x;
  if (e >= ET) return;
  int dst = (e < EE) ? ei[EE + e] : (e - EE);
  atomicAdd(&deg[dst], 1);
}

// pass 1: per-block (1024-elem chunk) exclusive scan + block sum
__global__ __launch_bounds__(256) void scan_part(const int* __restrict__ deg,
                                                 int* __restrict__ off,
                                                 int* __restrict__ bsum, int n){
  __shared__ int wtot[4];
  int tid = threadIdx.x, lane = tid & 63, w = tid >> 6;
  int i0 = blockIdx.x * SCAN_CHUNK + tid * 4;
  int v[4], s = 0;
  #pragma unroll
  for (int p = 0; p < 4; p++){ int i = i0 + p; v[p] = (i < n) ? deg[i] : 0; s += v[p]; }
  int sc = s;
  #pragma unroll
  for (int d = 1; d < 64; d <<= 1){ int t = __shfl_up(sc, d, 64); if (lane >= d) sc += t; }
  if (lane == 63) wtot[w] = sc;
  __syncthreads();
  int woff = 0;
  #pragma unroll
  for (int k = 0; k < 4; k++) if (k < w) woff += wtot[k];
  int excl = woff + sc - s;
  #pragma unroll
  for (int p = 0; p < 4; p++){
    int i = i0 + p;
    if (i < n) off[i] = excl;
    excl += v[p];
  }
  if (tid == 0) bsum[blockIdx.x] = wtot[0] + wtot[1] + wtot[2] + wtot[3];
}

// pass 2: exclusive scan of the <=64 block sums in one wave; total at bsum[nb]
__global__ __launch_bounds__(64) void scan_top(int* __restrict__ bsum, int nb){
  int lane = threadIdx.x;
  int v = (lane < nb) ? bsum[lane] : 0;
  int sc = v;
  #pragma unroll
  for (int d = 1; d < 64; d <<= 1){ int t = __shfl_up(sc, d, 64); if (lane >= d) sc += t; }
  if (lane < nb) bsum[lane] = sc - v;
  if (lane == 63) bsum[nb] = sc;    // grand total
}

// pass 3: add block offsets; mirror into cur; off[n] = total
__global__ __launch_bounds__(256) void scan_add(int* __restrict__ off,
                                                int* __restrict__ cur,
                                                const int* __restrict__ bsum, int n, int nb){
  int i0 = blockIdx.x * SCAN_CHUNK + threadIdx.x * 4;
  int add = bsum[blockIdx.x];
  #pragma unroll
  for (int p = 0; p < 4; p++){
    int j = i0 + p;
    if (j < n){ int t = off[j] + add; off[j] = t; cur[j] = t; }
  }
  if (blockIdx.x == 0 && threadIdx.x == 0) off[n] = bsum[nb];
}

__global__ void fill_csr(const int* __restrict__ ei, int* __restrict__ cur,
                         int* __restrict__ csr_src, int* __restrict__ csr_eid){
  int e = blockIdx.x * blockDim.x + threadIdx.x;
  if (e >= ET) return;
  int src, dst;
  if (e < EE){ src = ei[e]; dst = ei[EE + e]; } else { src = dst = e - EE; }
  int pos = atomicAdd(&cur[dst], 1);
  csr_src[pos] = src;
  csr_eid[pos] = e;
}

// ---------------- f32 tiled GEMM, bf16 C-store, fused attention-dot epilogue ----------------
// C[M,N] = A[M,K] @ B[K,N]; BM=64,BN=64,BK=32; 256 thr, 4x4/thread.
// C is stored as bf16 (ushort). es/ed computed from the f32 accumulators.
__global__ __launch_bounds__(256) void gemm_att(const float* __restrict__ A,
                                                const float* __restrict__ B,
                                                unsigned short* __restrict__ Cb,
                                                int M, int N, int K,
                                                const float* __restrict__ asrc,
                                                const float* __restrict__ adst,
                                                float* __restrict__ es,
                                                float* __restrict__ ed, int nh){
  constexpr int BM = 64, BN = 64, BK = 32;
  __shared__ float As[BK][BM + 1];
  __shared__ float Bs[BK][BN];
  int tid = threadIdx.x;
  int tx = tid & 15;        // 16
  int ty = tid >> 4;        // 16
  int row0 = blockIdx.y * BM;
  int col0 = blockIdx.x * BN;
  int head = blockIdx.x;
  float acc[4][4] = {};
  for (int k0 = 0; k0 < K; k0 += BK){
    #pragma unroll
    for (int l = 0; l < 2; l++){
      int i  = tid + l * 256;
      int r  = i >> 3;
      int c4 = (i & 7) * 4;
      float4 v = make_float4(0.f, 0.f, 0.f, 0.f);
      if (row0 + r < M)
        v = *(const float4*)&A[(size_t)(row0 + r) * K + k0 + c4];
      As[c4 + 0][r] = v.x; As[c4 + 1][r] = v.y; As[c4 + 2][r] = v.z; As[c4 + 3][r] = v.w;
    }
    #pragma unroll
    for (int l = 0; l < 2; l++){
      int i  = tid + l * 256;
      int r  = i >> 4;
      int c4 = (i & 15) * 4;
      float4 v = *(const float4*)&B[(size_t)(k0 + r) * N + col0 + c4];
      *(float4*)&Bs[r][c4] = v;
    }
    __syncthreads();
    #pragma unroll
    for (int kk = 0; kk < BK; kk++){
      float a[4];
      #pragma unroll
      for (int i = 0; i < 4; i++) a[i] = As[kk][ty * 4 + i];
      float4 bv = *(const float4*)&Bs[kk][tx * 4];
      float b[4] = {bv.x, bv.y, bv.z, bv.w};
      #pragma unroll
      for (int i = 0; i < 4; i++)
        #pragma unroll
        for (int j = 0; j < 4; j++)
          acc[i][j] = fmaf(a[i], b[j], acc[i][j]);
    }
    __syncthreads();
  }
  // bf16 C write (8 B per row-chunk)
  #pragma unroll
  for (int i = 0; i < 4; i++){
    int r = row0 + ty * 4 + i;
    if (r < M){
      uint2 p;
      p.x = bf16u(acc[i][0]) | (bf16u(acc[i][1]) << 16);
      p.y = bf16u(acc[i][2]) | (bf16u(acc[i][3]) << 16);
      *(uint2*)&Cb[(size_t)r * N + col0 + tx * 4] = p;
    }
  }
  // fused att dots: es[r,head] = sum_c H[r, head*64+c]*asrc[head,c] (same for ed)
  float4 av = *(const float4*)&asrc[head * 64 + tx * 4];
  float4 dv = *(const float4*)&adst[head * 64 + tx * 4];
  #pragma unroll
  for (int i = 0; i < 4; i++){
    float ps = acc[i][0]*av.x + acc[i][1]*av.y + acc[i][2]*av.z + acc[i][3]*av.w;
    float pd = acc[i][0]*dv.x + acc[i][1]*dv.y + acc[i][2]*dv.z + acc[i][3]*dv.w;
    #pragma unroll
    for (int o = 1; o < 16; o <<= 1){
      ps += __shfl_xor(ps, o, 64);
      pd += __shfl_xor(pd, o, 64);
    }
    int r = row0 + ty * 4 + i;
    if (tx == 0 && r < M){
      es[(size_t)r * nh + head] = ps;
      ed[(size_t)r * nh + head] = pd;
    }
  }
}

// ---------------- layer-1 aggregation (bf16 H1 gather) ----------------
__global__ __launch_bounds__(256) void agg1_kernel(const int* __restrict__ off,
                                                   const int* __restrict__ csr_src,
                                                   const unsigned short* __restrict__ H1b,
                                                   const float* __restrict__ es,
                                                   const float* __restrict__ ed,
                                                   const float* __restrict__ b1,
                                                   const float* __restrict__ lng,
                                                   const float* __restrict__ lnb,
                                                   float* __restrict__ h1out, int n){
  __shared__ float wsh4[4][64][4];
  __shared__ int   ssh[4][64];
  int wv   = threadIdx.x >> 6;
  int wid  = (blockIdx.x * blockDim.x + threadIdx.x) >> 6;
  int lane = threadIdx.x & 63;
  if (wid >= n) return;
  int s0  = off[wid];
  int deg = off[wid + 1] - s0;
  const float4 edv = *(const float4*)(ed + (size_t)wid * 4);

  float v0, v1, v2, v3;

  if (deg <= 64){
    bool vld = lane < deg;
    int srcl = vld ? csr_src[s0 + lane] : 0;
    float4 e4 = vld ? *(const float4*)(es + (size_t)srcl * 4)
                    : make_float4(-1e30f, -1e30f, -1e30f, -1e30f);
    float e0 = vld ? lrelu(e4.x + edv.x) : -1e30f;
    float e1 = vld ? lrelu(e4.y + edv.y) : -1e30f;
    float e2 = vld ? lrelu(e4.z + edv.z) : -1e30f;
    float e3 = vld ? lrelu(e4.w + edv.w) : -1e30f;
    float m0 = wmaxr(e0), m1 = wmaxr(e1), m2 = wmaxr(e2), m3 = wmaxr(e3);
    float w0 = vld ? __expf(e0 - m0) : 0.f;
    float w1 = vld ? __expf(e1 - m1) : 0.f;
    float w2 = vld ? __expf(e2 - m2) : 0.f;
    float w3 = vld ? __expf(e3 - m3) : 0.f;
    w0 /= (wsum(w0) + 1e-16f);
    w1 /= (wsum(w1) + 1e-16f);
    w2 /= (wsum(w2) + 1e-16f);
    w3 /= (wsum(w3) + 1e-16f);
    ssh[wv][lane] = srcl;
    *(float4*)&wsh4[wv][lane][0] = make_float4(w0, w1, w2, w3);
    __builtin_amdgcn_wave_barrier();   // same-wave DS in-order; pin compiler order

    int h = lane >> 4;
    float ax = 0.f, ay = 0.f, az = 0.f, aw = 0.f;
    int t = 0;
    for (; t + 4 <= deg; t += 4){
      int a0 = ssh[wv][t],     a1 = ssh[wv][t + 1];
      int a2 = ssh[wv][t + 2], a3 = ssh[wv][t + 3];
      float q0 = wsh4[wv][t][h],     q1 = wsh4[wv][t + 1][h];
      float q2 = wsh4[wv][t + 2][h], q3 = wsh4[wv][t + 3][h];
      uint2 g0 = *(const uint2*)(H1b + (size_t)a0 * 256 + lane * 4);
      uint2 g1 = *(const uint2*)(H1b + (size_t)a1 * 256 + lane * 4);
      uint2 g2 = *(const uint2*)(H1b + (size_t)a2 * 256 + lane * 4);
      uint2 g3 = *(const uint2*)(H1b + (size_t)a3 * 256 + lane * 4);
      ax = fmaf(__uint_as_float(g0.x << 16),        q0, ax);
      ay = fmaf(__uint_as_float(g0.x & 0xffff0000u), q0, ay);
      az = fmaf(__uint_as_float(g0.y << 16),        q0, az);
      aw = fmaf(__uint_as_float(g0.y & 0xffff0000u), q0, aw);
      ax = fmaf(__uint_as_float(g1.x << 16),        q1, ax);
      ay = fmaf(__uint_as_float(g1.x & 0xffff0000u), q1, ay);
      az = fmaf(__uint_as_float(g1.y << 16),        q1, az);
      aw = fmaf(__uint_as_float(g1.y & 0xffff0000u), q1, aw);
      ax = fmaf(__uint_as_float(g2.x << 16),        q2, ax);
      ay = fmaf(__uint_as_float(g2.x & 0xffff0000u), q2, ay);
      az = fmaf(__uint_as_float(g2.y << 16),        q2, az);
      aw = fmaf(__uint_as_float(g2.y & 0xffff0000u), q2, aw);
      ax = fmaf(__uint_as_float(g3.x << 16),        q3, ax);
      ay = fmaf(__uint_as_float(g3.x & 0xffff0000u), q3, ay);
      az = fmaf(__uint_as_float(g3.y << 16),        q3, az);
      aw = fmaf(__uint_as_float(g3.y & 0xffff0000u), q3, aw);
    }
    for (; t < deg; t++){
      int a0 = ssh[wv][t];
      float q0 = wsh4[wv][t][h];
      uint2 g0 = *(const uint2*)(H1b + (size_t)a0 * 256 + lane * 4);
      ax = fmaf(__uint_as_float(g0.x << 16),        q0, ax);
      ay = fmaf(__uint_as_float(g0.x & 0xffff0000u), q0, ay);
      az = fmaf(__uint_as_float(g0.y << 16),        q0, az);
      aw = fmaf(__uint_as_float(g0.y & 0xffff0000u), q0, aw);
    }
    float4 bb = *(const float4*)(b1 + lane * 4);
    v0 = eluf(ax + bb.x); v1 = eluf(ay + bb.y);
    v2 = eluf(az + bb.z); v3 = eluf(aw + bb.w);
    float mu = wsum(v0 + v1 + v2 + v3) * (1.f/256.f);
    float q  = (v0-mu)*(v0-mu) + (v1-mu)*(v1-mu) + (v2-mu)*(v2-mu) + (v3-mu)*(v3-mu);
    float rstd = rsqrtf(wsum(q) * (1.f/256.f) + 1e-5f);
    float4 g4 = *(const float4*)(lng + lane * 4);
    float4 bo = *(const float4*)(lnb + lane * 4);
    float4 o4 = make_float4((v0-mu)*rstd*g4.x + bo.x, (v1-mu)*rstd*g4.y + bo.y,
                            (v2-mu)*rstd*g4.z + bo.z, (v3-mu)*rstd*g4.w + bo.w);
    *(float4*)(h1out + (size_t)wid * 256 + lane * 4) = o4;
    return;
  }

  // slow path: deg > 64 (rare); channel layout: lane = channel within head
  float m0 = -1e30f, m1 = -1e30f, m2 = -1e30f, m3 = -1e30f;
  for (int j = lane; j < deg; j += 64){
    int src = csr_src[s0 + j];
    float4 e4 = *(const float4*)(es + (size_t)src * 4);
    m0 = fmaxf(m0, lrelu(e4.x + edv.x));
    m1 = fmaxf(m1, lrelu(e4.y + edv.y));
    m2 = fmaxf(m2, lrelu(e4.z + edv.z));
    m3 = fmaxf(m3, lrelu(e4.w + edv.w));
  }
  m0 = wmaxr(m0); m1 = wmaxr(m1); m2 = wmaxr(m2); m3 = wmaxr(m3);
  float acc0 = 0.f, acc1 = 0.f, acc2 = 0.f, acc3 = 0.f;
  float den0 = 0.f, den1 = 0.f, den2 = 0.f, den3 = 0.f;
  for (int j = 0; j < deg; j++){
    int src = csr_src[s0 + j];
    float4 e4 = *(const float4*)(es + (size_t)src * 4);
    float x0 = __expf(lrelu(e4.x + edv.x) - m0);
    float x1 = __expf(lrelu(e4.y + edv.y) - m1);
    float x2 = __expf(lrelu(e4.z + edv.z) - m2);
    float x3 = __expf(lrelu(e4.w + edv.w) - m3);
    den0 += x0; den1 += x1; den2 += x2; den3 += x3;
    const unsigned short* hp = H1b + (size_t)src * 256;
    acc0 = fmaf(bfl(hp[lane]),       x0, acc0);
    acc1 = fmaf(bfl(hp[64 + lane]),  x1, acc1);
    acc2 = fmaf(bfl(hp[128 + lane]), x2, acc2);
    acc3 = fmaf(bfl(hp[192 + lane]), x3, acc3);
  }
  v0 = eluf(acc0 / (den0 + 1e-16f) + b1[lane]);
  v1 = eluf(acc1 / (den1 + 1e-16f) + b1[64 + lane]);
  v2 = eluf(acc2 / (den2 + 1e-16f) + b1[128 + lane]);
  v3 = eluf(acc3 / (den3 + 1e-16f) + b1[192 + lane]);
  float mu = wsum(v0 + v1 + v2 + v3) * (1.f/256.f);
  float q  = (v0-mu)*(v0-mu) + (v1-mu)*(v1-mu) + (v2-mu)*(v2-mu) + (v3-mu)*(v3-mu);
  float rstd = rsqrtf(wsum(q) * (1.f/256.f) + 1e-5f);
  float* o = h1out + (size_t)wid * 256;
  o[lane]       = (v0-mu)*rstd*lng[lane]       + lnb[lane];
  o[64 + lane]  = (v1-mu)*rstd*lng[64 + lane]  + lnb[64 + lane];
  o[128 + lane] = (v2-mu)*rstd*lng[128 + lane] + lnb[128 + lane];
  o[192 + lane] = (v3-mu)*rstd*lng[192 + lane] + lnb[192 + lane];
}

// ---------------- layer-2 aggregation (1 head, bf16 H2 gather) ----------------
__global__ __launch_bounds__(256) void agg2_kernel(const int* __restrict__ off,
                                                   const int* __restrict__ csr_src,
                                                   const int* __restrict__ csr_eid,
                                                   const unsigned short* __restrict__ H2b,
                                                   const float* __restrict__ es,
                                                   const float* __restrict__ ed,
                                                   const float* __restrict__ b2,
                                                   const float* __restrict__ lng,
                                                   const float* __restrict__ lnb,
                                                   float* __restrict__ h2out,
                                                   float* __restrict__ alpha_out, int n){
  int wid  = (blockIdx.x * blockDim.x + threadIdx.x) >> 6;
  int lane = threadIdx.x & 63;
  if (wid >= n) return;
  int s0  = off[wid];
  int deg = off[wid + 1] - s0;
  float edv = ed[wid];
  float acc = 0.f;

  if (deg <= 64){
    bool vld = lane < deg;
    int srcl = vld ? csr_src[s0 + lane] : 0;
    float el = vld ? lrelu(es[srcl] + edv) : -1e30f;
    float m  = wmaxr(el);
    float w  = vld ? __expf(el - m) : 0.f;
    float den = wsum(w) + 1e-16f;
    float wl = w / den;
    if (vld) alpha_out[csr_eid[s0 + lane]] = wl;
    int t = 0;
    for (; t + 4 <= deg; t += 4){
      int a0 = __shfl(srcl, t, 64),   a1 = __shfl(srcl, t+1, 64);
      int a2 = __shfl(srcl, t+2, 64), a3 = __shfl(srcl, t+3, 64);
      float q0 = __shfl(wl, t, 64),   q1 = __shfl(wl, t+1, 64);
      float q2 = __shfl(wl, t+2, 64), q3 = __shfl(wl, t+3, 64);
      float h0 = bfl(H2b[(size_t)a0 * 64 + lane]);
      float h1v = bfl(H2b[(size_t)a1 * 64 + lane]);
      float h2v = bfl(H2b[(size_t)a2 * 64 + lane]);
      float h3 = bfl(H2b[(size_t)a3 * 64 + lane]);
      acc = fmaf(h0, q0, acc); acc = fmaf(h1v, q1, acc);
      acc = fmaf(h2v, q2, acc); acc = fmaf(h3, q3, acc);
    }
    for (; t < deg; t++){
      int a0 = __shfl(srcl, t, 64);
      float q0 = __shfl(wl, t, 64);
      acc = fmaf(bfl(H2b[(size_t)a0 * 64 + lane]), q0, acc);
    }
  } else {
    float m = -1e30f;
    for (int j = lane; j < deg; j += 64){
      int src = csr_src[s0 + j];
      m = fmaxf(m, lrelu(es[src] + edv));
    }
    m = wmaxr(m);
    float den = 0.f;
    for (int j = lane; j < deg; j += 64){
      int src = csr_src[s0 + j];
      den += __expf(lrelu(es[src] + edv) - m);
    }
    den = wsum(den) + 1e-16f;
    for (int j = 0; j < deg; j++){
      int src = csr_src[s0 + j];
      float a = __expf(lrelu(es[src] + edv) - m) / den;
      if (lane == 0) alpha_out[csr_eid[s0 + j]] = a;
      acc = fmaf(bfl(H2b[(size_t)src * 64 + lane]), a, acc);
    }
  }
  float v  = acc + b2[lane];
  float mu = wsum(v) * (1.f/64.f);
  float d  = v - mu;
  float rstd = rsqrtf(wsum(d*d) * (1.f/64.f) + 1e-5f);
  h2out[(size_t)wid * 64 + lane] = d * rstd * lng[lane] + lnb[lane];
}

// ---------------- head: step/sentence MLP + dueling head ----------------
__global__ __launch_bounds__(64) void head_kernel(const float* __restrict__ semb,
                                                  const int* __restrict__ active,
                                                  const int* __restrict__ step,
                                                  const float* __restrict__ fc0w, const float* __restrict__ fc0b,
                                                  const float* __restrict__ fc1w, const float* __restrict__ fc1b,
                                                  const float* __restrict__ fc2w, const float* __restrict__ fc2b,
                                                  const float* __restrict__ fc3w, const float* __restrict__ fc3b,
                                                  const float* __restrict__ valw, const float* __restrict__ valb,
                                                  const float* __restrict__ advw, const float* __restrict__ advb,
                                                  const float* __restrict__ lnhg, const float* __restrict__ lnhb,
                                                  const float* __restrict__ lnfg, const float* __restrict__ lnfb,
                                                  const float* __restrict__ h2,
                                                  float* __restrict__ out){
  int t = threadIdx.x;  // one wave of 64
  __shared__ float sh[128];

  float sval = (float)(step[0] + 1) * 0.01f;
  float stepsv = ln64(fmaxf(fmaf(sval, fc0w[t], fc0b[t]), 0.f), lnhg, lnhb, t);

  float acc = fc1b[t];
  #pragma unroll 8
  for (int k = 0; k < 768; k++) acc = fmaf(semb[k], fc1w[k * 64 + t], acc);
  float sentv = ln64(fmaxf(acc, 0.f), lnhg, lnhb, t) + stepsv;
  sh[t] = sentv;
  __syncthreads();
  float acc2 = fc2b[t];
  #pragma unroll 8
  for (int k = 0; k < 64; k++) acc2 = fmaf(sh[k], fc2w[k * 64 + t], acc2);
  __syncthreads();
  float sent2 = ln64(fmaxf(acc2, 0.f), lnhg, lnhb, t);

  float a0 = h2[(size_t)active[0] * 64 + t];
  float a1 = sent2;
  float mu = wsum(a0 + a1) * (1.f/128.f);
  float q  = (a0-mu)*(a0-mu) + (a1-mu)*(a1-mu);
  float rstd = rsqrtf(wsum(q) * (1.f/128.f) + 1e-5f);
  float n0 = (a0-mu)*rstd*lnfg[t]      + lnfb[t];
  float n1 = (a1-mu)*rstd*lnfg[64 + t] + lnfb[64 + t];
  sh[t] = n0; sh[64 + t] = n1;
  __syncthreads();

  float acc3 = fc3b[t];
  #pragma unroll 8
  for (int k = 0; k < 128; k++) acc3 = fmaf(sh[k], fc3w[k * 64 + t], acc3);
  float a2v = ln64(fmaxf(acc3, 0.f), lnhg, lnhb, t);
  __syncthreads();
  sh[t] = a2v;
  __syncthreads();

  float val = wsum(a2v * valw[t]) + valb[0];
  float advv = 0.f;
  if (t < 32){
    advv = advb[t];
    #pragma unroll 8
    for (int k = 0; k < 64; k++) advv = fmaf(sh[k], advw[k * 32 + t], advv);
  }
  float am = wsum(t < 32 ? advv : 0.f) * (1.f/32.f);
  if (t < 32) out[t] = tanhf(val + advv - am);
}

extern "C" void kernel_launch(void* const* d_in, const int* in_sizes, int n_in,
                              void* d_out, int out_size, void* d_ws, size_t ws_size,
                              hipStream_t stream) {
  const float* x     = (const float*)d_in[0];
  const int*   ei    = (const int*)  d_in[1];
  const float* semb  = (const float*)d_in[2];
  const int*   act   = (const int*)  d_in[3];
  const int*   step  = (const int*)  d_in[4];
  const float* W1    = (const float*)d_in[5];
  const float* as1   = (const float*)d_in[6];
  const float* ad1   = (const float*)d_in[7];
  const float* b1    = (const float*)d_in[8];
  const float* W2    = (const float*)d_in[9];
  const float* as2   = (const float*)d_in[10];
  const float* ad2   = (const float*)d_in[11];
  const float* b2    = (const float*)d_in[12];
  const float* fc0w  = (const float*)d_in[13];
  const float* fc0b  = (const float*)d_in[14];
  const float* fc1w  = (const float*)d_in[15];
  const float* fc1b  = (const float*)d_in[16];
  const float* fc2w  = (const float*)d_in[17];
  const float* fc2b  = (const float*)d_in[18];
  const float* fc3w  = (const float*)d_in[19];
  const float* fc3b  = (const float*)d_in[20];
  const float* valw  = (const float*)d_in[21];
  const float* valb  = (const float*)d_in[22];
  const float* advw  = (const float*)d_in[23];
  const float* advb  = (const float*)d_in[24];
  const float* lnhg  = (const float*)d_in[25];
  const float* lnhb  = (const float*)d_in[26];
  const float* lnfg  = (const float*)d_in[27];
  const float* lnfb  = (const float*)d_in[28];
  const float* lnag  = (const float*)d_in[29];
  const float* lnab  = (const float*)d_in[30];

  char* ws = (char*)d_ws;
  size_t o = 0;
  auto alloc = [&](size_t bytes) -> void* {
    o = (o + 255) & ~(size_t)255;
    void* p = ws + o;
    o += bytes;
    return p;
  };
  int*   deg     = (int*)  alloc((size_t)(NN + 1) * 4);
  int*   off     = (int*)  alloc((size_t)(NN + 1) * 4);
  int*   cur     = (int*)  alloc((size_t)NN * 4);
  int*   bsum    = (int*)  alloc((size_t)(SCAN_NB + 1) * 4);
  int*   csr_src = (int*)  alloc((size_t)ET * 4);
  int*   csr_eid = (int*)  alloc((size_t)ET * 4);
  unsigned short* H1b = (unsigned short*)alloc((size_t)NN * 256 * 2);  // bf16 H1
  float* h1      = (float*)alloc((size_t)NN * 256 * 4);
  float* es1     = (float*)alloc((size_t)NN * 16);
  float* ed1     = (float*)alloc((size_t)NN * 16);
  unsigned short* H2b = H1b;   // aliases; lifetimes don't overlap
  float* es2 = es1;
  float* ed2 = ed1;

  float* logits    = (float*)d_out;
  float* h2out     = (float*)d_out + 32;
  float* alpha_out = (float*)d_out + 32 + (size_t)NN * 64;

  // CSR build
  hipMemsetAsync(deg, 0, (size_t)NN * 4, stream);
  degree_kernel<<<(ET + 255) / 256, 256, 0, stream>>>(ei, deg);
  scan_part<<<SCAN_NB, 256, 0, stream>>>(deg, off, bsum, NN);
  scan_top <<<1, 64, 0, stream>>>(bsum, SCAN_NB);
  scan_add <<<SCAN_NB, 256, 0, stream>>>(off, cur, bsum, NN, SCAN_NB);
  fill_csr<<<(ET + 255) / 256, 256, 0, stream>>>(ei, cur, csr_src, csr_eid);

  // layer 1 (att dots fused into gemm epilogue; C stored bf16)
  gemm_att<<<dim3(4, (NN + 63) / 64), 256, 0, stream>>>(x, W1, H1b, NN, 256, 128,
                                                        as1, ad1, es1, ed1, 4);
  agg1_kernel<<<NN / 4, 256, 0, stream>>>(off, csr_src, H1b, es1, ed1, b1, lnag, lnab, h1, NN);

  // layer 2
  gemm_att<<<dim3(1, (NN + 63) / 64), 256, 0, stream>>>(h1, W2, H2b, NN, 64, 256,
                                                        as2, ad2, es2, ed2, 1);
  agg2_kernel<<<NN / 4, 256, 0, stream>>>(off, csr_src, csr_eid, H2b, es2, ed2, b2,
                                          lnhg, lnhb, h2out, alpha_out, NN);

  // head
  head_kernel<<<1, 64, 0, stream>>>(semb, act, step,
                                    fc0w, fc0b, fc1w, fc1b, fc2w, fc2b, fc3w, fc3b,
                                    valw, valb, advw, advb,
                                    lnhg, lnhb, lnfg, lnfb,
                                    h2out, logits);
}

// Round 5
// 393.509 us; speedup vs baseline: 1.6388x; 1.1055x over previous
//
#include <hip/hip_runtime.h>
#include <cstdint>
#include <cstddef>

#define DEV __device__ __forceinline__

static constexpr int NN  = 50000;
static constexpr int EE  = 600000;
static constexpr int ET  = 650000;   // EE + NN self loops
static constexpr int SCAN_CHUNK = 1024;                 // 256 threads x 4
static constexpr int SCAN_NB = (NN + SCAN_CHUNK - 1) / SCAN_CHUNK;   // 49

typedef __attribute__((ext_vector_type(8))) short bf16x8;   // 8 bf16 (4 VGPR)
typedef __attribute__((ext_vector_type(4))) float f32x4;    // MFMA acc
typedef __attribute__((ext_vector_type(4))) int   i32x4;

DEV float wsum(float v){
  #pragma unroll
  for (int o = 32; o > 0; o >>= 1) v += __shfl_xor(v, o, 64);
  return v;
}
DEV float wmaxr(float v){
  #pragma unroll
  for (int o = 32; o > 0; o >>= 1) v = fmaxf(v, __shfl_xor(v, o, 64));
  return v;
}
DEV float lrelu(float x){ return x > 0.f ? x : 0.2f * x; }
DEV float eluf(float x){ return x > 0.f ? x : expm1f(x); }
DEV float ln64(float v, const float* g, const float* b, int lane){
  float mu  = wsum(v) * (1.f/64.f);
  float d   = v - mu;
  float var = wsum(d*d) * (1.f/64.f);
  return d * rsqrtf(var + 1e-5f) * g[lane] + b[lane];
}
// f32 -> bf16 (RNE) as raw ushort bits
DEV unsigned int bf16u(float f){
  unsigned int u = __float_as_uint(f);
  return (u + 0x7fffu + ((u >> 16) & 1u)) >> 16;
}
DEV float bfl(unsigned int lo16){ return __uint_as_float(lo16 << 16); }

// ---------------- CSR build ----------------
__global__ void degree_kernel(const int* __restrict__ ei, int* __restrict__ deg){
  int e = blockIdx.x * blockDim.x + threadIdx.x;
  if (e >= ET) return;
  int dst = (e < EE) ? ei[EE + e] : (e - EE);
  atomicAdd(&deg[dst], 1);
}

__global__ __launch_bounds__(256) void scan_part(const int* __restrict__ deg,
                                                 int* __restrict__ off,
                                                 int* __restrict__ bsum, int n){
  __shared__ int wtot[4];
  int tid = threadIdx.x, lane = tid & 63, w = tid >> 6;
  int i0 = blockIdx.x * SCAN_CHUNK + tid * 4;
  int v[4], s = 0;
  #pragma unroll
  for (int p = 0; p < 4; p++){ int i = i0 + p; v[p] = (i < n) ? deg[i] : 0; s += v[p]; }
  int sc = s;
  #pragma unroll
  for (int d = 1; d < 64; d <<= 1){ int t = __shfl_up(sc, d, 64); if (lane >= d) sc += t; }
  if (lane == 63) wtot[w] = sc;
  __syncthreads();
  int woff = 0;
  #pragma unroll
  for (int k = 0; k < 4; k++) if (k < w) woff += wtot[k];
  int excl = woff + sc - s;
  #pragma unroll
  for (int p = 0; p < 4; p++){
    int i = i0 + p;
    if (i < n) off[i] = excl;
    excl += v[p];
  }
  if (tid == 0) bsum[blockIdx.x] = wtot[0] + wtot[1] + wtot[2] + wtot[3];
}

__global__ __launch_bounds__(64) void scan_top(int* __restrict__ bsum, int nb){
  int lane = threadIdx.x;
  int v = (lane < nb) ? bsum[lane] : 0;
  int sc = v;
  #pragma unroll
  for (int d = 1; d < 64; d <<= 1){ int t = __shfl_up(sc, d, 64); if (lane >= d) sc += t; }
  if (lane < nb) bsum[lane] = sc - v;
  if (lane == 63) bsum[nb] = sc;    // grand total
}

__global__ __launch_bounds__(256) void scan_add(int* __restrict__ off,
                                                int* __restrict__ cur,
                                                const int* __restrict__ bsum, int n, int nb){
  int i0 = blockIdx.x * SCAN_CHUNK + threadIdx.x * 4;
  int add = bsum[blockIdx.x];
  #pragma unroll
  for (int p = 0; p < 4; p++){
    int j = i0 + p;
    if (j < n){ int t = off[j] + add; off[j] = t; cur[j] = t; }
  }
  if (blockIdx.x == 0 && threadIdx.x == 0) off[n] = bsum[nb];
}

__global__ void fill_csr(const int* __restrict__ ei, int* __restrict__ cur,
                         int* __restrict__ csr_src, int* __restrict__ csr_eid){
  int e = blockIdx.x * blockDim.x + threadIdx.x;
  if (e >= ET) return;
  int src, dst;
  if (e < EE){ src = ei[e]; dst = ei[EE + e]; } else { src = dst = e - EE; }
  int pos = atomicAdd(&cur[dst], 1);
  csr_src[pos] = src;
  csr_eid[pos] = e;
}

// ---------------- W pack: f32 K×N -> MFMA A-operand frags (bf16) ----------------
// Wp[(mb*ksteps + ks)*64 + lane][j] = bf16( W[ks*32 + (lane>>4)*8 + j][mb*16 + (lane&15)] )
__global__ __launch_bounds__(256) void pack_w(const float* __restrict__ W,
                                              short* __restrict__ Wp, int K, int N){
  int tid = blockIdx.x * blockDim.x + threadIdx.x;
  int ksteps = K >> 5;
  int total = (N >> 4) * ksteps * 64;
  if (tid >= total) return;
  int lane = tid & 63;
  int ks   = (tid >> 6) % ksteps;
  int mb   = (tid >> 6) / ksteps;
  int col  = mb * 16 + (lane & 15);
  int krow = ks * 32 + (lane >> 4) * 8;
  short v[8];
  #pragma unroll
  for (int j = 0; j < 8; j++) v[j] = (short)bf16u(W[(size_t)(krow + j) * N + col]);
  #pragma unroll
  for (int j = 0; j < 8; j++) Wp[(size_t)tid * 8 + j] = v[j];
}

// ---------------- MFMA GEMM (LDS-free) + bf16 C-store + fused att dots ----------------
// D[N_out x nodes] computed as A(Wp: N_out x K) * B(X^T: K x nodes) per 16x16x32 mfma.
// Wave covers 16 nodes (n = lane&15); quad = lane>>4. acc[mb][r]: h1col = mb*16+quad*4+r.
template<int KSTEPS, int MBLKS, int NH, bool INF32>
__global__ __launch_bounds__(256) void mfma_gemm_att(const short* __restrict__ Wp,
                                                     const float* __restrict__ Xf,
                                                     const unsigned short* __restrict__ Xh,
                                                     unsigned short* __restrict__ Cb,
                                                     const float* __restrict__ asrc,
                                                     const float* __restrict__ adst,
                                                     float* __restrict__ es,
                                                     float* __restrict__ ed, int M){
  constexpr int K = KSTEPS * 32, N = MBLKS * 16;
  int lane  = threadIdx.x & 63;
  int wv    = threadIdx.x >> 6;
  int quad  = lane >> 4;
  int node  = blockIdx.x * 64 + wv * 16 + (lane & 15);
  bool nv   = node < M;
  int nodec = nv ? node : M - 1;

  f32x4 acc[MBLKS];
  #pragma unroll
  for (int m = 0; m < MBLKS; m++) acc[m] = (f32x4){0.f, 0.f, 0.f, 0.f};

  #pragma unroll
  for (int ks = 0; ks < KSTEPS; ks++){
    int k0 = ks * 32 + quad * 8;
    bf16x8 bfrag;
    if (INF32){
      float4 u = *(const float4*)(Xf + (size_t)nodec * K + k0);
      float4 v = *(const float4*)(Xf + (size_t)nodec * K + k0 + 4);
      i32x4 bi;
      bi.x = (int)(bf16u(u.x) | (bf16u(u.y) << 16));
      bi.y = (int)(bf16u(u.z) | (bf16u(u.w) << 16));
      bi.z = (int)(bf16u(v.x) | (bf16u(v.y) << 16));
      bi.w = (int)(bf16u(v.z) | (bf16u(v.w) << 16));
      bfrag = __builtin_bit_cast(bf16x8, bi);
    } else {
      bfrag = *(const bf16x8*)(Xh + (size_t)nodec * K + k0);
    }
    #pragma unroll
    for (int mb = 0; mb < MBLKS; mb++){
      bf16x8 afrag = *(const bf16x8*)(Wp + ((size_t)(mb * KSTEPS + ks) * 64 + lane) * 8);
      acc[mb] = __builtin_amdgcn_mfma_f32_16x16x32_bf16(afrag, bfrag, acc[mb], 0, 0, 0);
    }
  }

  // bf16 C write: lane's 4 accs are consecutive h1cols -> one 8B store per mb
  if (nv){
    unsigned short* crow = Cb + (size_t)node * N;
    #pragma unroll
    for (int mb = 0; mb < MBLKS; mb++){
      uint2 p;
      p.x = bf16u(acc[mb][0]) | (bf16u(acc[mb][1]) << 16);
      p.y = bf16u(acc[mb][2]) | (bf16u(acc[mb][3]) << 16);
      *(uint2*)(crow + mb * 16 + quad * 4) = p;
    }
  }

  // fused att dots (per head), reduce across quads
  float ps[NH], pd[NH];
  #pragma unroll
  for (int h = 0; h < NH; h++){ ps[h] = 0.f; pd[h] = 0.f; }
  #pragma unroll
  for (int mb = 0; mb < MBLKS; mb++){
    int h = (NH == 1) ? 0 : (mb >> 2);
    #pragma unroll
    for (int r = 0; r < 4; r++){
      int c = mb * 16 + quad * 4 + r;
      ps[h] = fmaf(acc[mb][r], asrc[c], ps[h]);
      pd[h] = fmaf(acc[mb][r], adst[c], pd[h]);
    }
  }
  #pragma unroll
  for (int h = 0; h < NH; h++){
    ps[h] += __shfl_xor(ps[h], 16, 64); ps[h] += __shfl_xor(ps[h], 32, 64);
    pd[h] += __shfl_xor(pd[h], 16, 64); pd[h] += __shfl_xor(pd[h], 32, 64);
  }
  if (quad == 0 && nv){
    if (NH == 4){
      *(float4*)(es + (size_t)node * 4) = make_float4(ps[0], ps[1], ps[2], ps[3]);
      *(float4*)(ed + (size_t)node * 4) = make_float4(pd[0], pd[1], pd[2], pd[3]);
    } else {
      es[node] = ps[0];
      ed[node] = pd[0];
    }
  }
}

// ---------------- layer-1 aggregation (bf16 H1 gather, bf16 h1 out) ----------------
__global__ __launch_bounds__(256) void agg1_kernel(const int* __restrict__ off,
                                                   const int* __restrict__ csr_src,
                                                   const unsigned short* __restrict__ H1b,
                                                   const float* __restrict__ es,
                                                   const float* __restrict__ ed,
                                                   const float* __restrict__ b1,
                                                   const float* __restrict__ lng,
                                                   const float* __restrict__ lnb,
                                                   unsigned short* __restrict__ h1b, int n){
  __shared__ float wsh4[4][64][4];
  __shared__ int   ssh[4][64];
  int wv   = threadIdx.x >> 6;
  int wid  = (blockIdx.x * blockDim.x + threadIdx.x) >> 6;
  int lane = threadIdx.x & 63;
  if (wid >= n) return;
  int s0  = off[wid];
  int deg = off[wid + 1] - s0;
  const float4 edv = *(const float4*)(ed + (size_t)wid * 4);

  float v0, v1, v2, v3;

  if (deg <= 64){
    bool vld = lane < deg;
    int srcl = vld ? csr_src[s0 + lane] : 0;
    float4 e4 = vld ? *(const float4*)(es + (size_t)srcl * 4)
                    : make_float4(-1e30f, -1e30f, -1e30f, -1e30f);
    float e0 = vld ? lrelu(e4.x + edv.x) : -1e30f;
    float e1 = vld ? lrelu(e4.y + edv.y) : -1e30f;
    float e2 = vld ? lrelu(e4.z + edv.z) : -1e30f;
    float e3 = vld ? lrelu(e4.w + edv.w) : -1e30f;
    float m0 = wmaxr(e0), m1 = wmaxr(e1), m2 = wmaxr(e2), m3 = wmaxr(e3);
    float w0 = vld ? __expf(e0 - m0) : 0.f;
    float w1 = vld ? __expf(e1 - m1) : 0.f;
    float w2 = vld ? __expf(e2 - m2) : 0.f;
    float w3 = vld ? __expf(e3 - m3) : 0.f;
    w0 /= (wsum(w0) + 1e-16f);
    w1 /= (wsum(w1) + 1e-16f);
    w2 /= (wsum(w2) + 1e-16f);
    w3 /= (wsum(w3) + 1e-16f);
    ssh[wv][lane] = srcl;
    *(float4*)&wsh4[wv][lane][0] = make_float4(w0, w1, w2, w3);
    __builtin_amdgcn_wave_barrier();   // same-wave DS in-order; pin compiler order

    int h = lane >> 4;
    float ax = 0.f, ay = 0.f, az = 0.f, aw = 0.f;
    int t = 0;
    for (; t + 4 <= deg; t += 4){
      int a0 = ssh[wv][t],     a1 = ssh[wv][t + 1];
      int a2 = ssh[wv][t + 2], a3 = ssh[wv][t + 3];
      float q0 = wsh4[wv][t][h],     q1 = wsh4[wv][t + 1][h];
      float q2 = wsh4[wv][t + 2][h], q3 = wsh4[wv][t + 3][h];
      uint2 g0 = *(const uint2*)(H1b + (size_t)a0 * 256 + lane * 4);
      uint2 g1 = *(const uint2*)(H1b + (size_t)a1 * 256 + lane * 4);
      uint2 g2 = *(const uint2*)(H1b + (size_t)a2 * 256 + lane * 4);
      uint2 g3 = *(const uint2*)(H1b + (size_t)a3 * 256 + lane * 4);
      ax = fmaf(__uint_as_float(g0.x << 16),        q0, ax);
      ay = fmaf(__uint_as_float(g0.x & 0xffff0000u), q0, ay);
      az = fmaf(__uint_as_float(g0.y << 16),        q0, az);
      aw = fmaf(__uint_as_float(g0.y & 0xffff0000u), q0, aw);
      ax = fmaf(__uint_as_float(g1.x << 16),        q1, ax);
      ay = fmaf(__uint_as_float(g1.x & 0xffff0000u), q1, ay);
      az = fmaf(__uint_as_float(g1.y << 16),        q1, az);
      aw = fmaf(__uint_as_float(g1.y & 0xffff0000u), q1, aw);
      ax = fmaf(__uint_as_float(g2.x << 16),        q2, ax);
      ay = fmaf(__uint_as_float(g2.x & 0xffff0000u), q2, ay);
      az = fmaf(__uint_as_float(g2.y << 16),        q2, az);
      aw = fmaf(__uint_as_float(g2.y & 0xffff0000u), q2, aw);
      ax = fmaf(__uint_as_float(g3.x << 16),        q3, ax);
      ay = fmaf(__uint_as_float(g3.x & 0xffff0000u), q3, ay);
      az = fmaf(__uint_as_float(g3.y << 16),        q3, az);
      aw = fmaf(__uint_as_float(g3.y & 0xffff0000u), q3, aw);
    }
    for (; t < deg; t++){
      int a0 = ssh[wv][t];
      float q0 = wsh4[wv][t][h];
      uint2 g0 = *(const uint2*)(H1b + (size_t)a0 * 256 + lane * 4);
      ax = fmaf(__uint_as_float(g0.x << 16),        q0, ax);
      ay = fmaf(__uint_as_float(g0.x & 0xffff0000u), q0, ay);
      az = fmaf(__uint_as_float(g0.y << 16),        q0, az);
      aw = fmaf(__uint_as_float(g0.y & 0xffff0000u), q0, aw);
    }
    float4 bb = *(const float4*)(b1 + lane * 4);
    v0 = eluf(ax + bb.x); v1 = eluf(ay + bb.y);
    v2 = eluf(az + bb.z); v3 = eluf(aw + bb.w);
    float mu = wsum(v0 + v1 + v2 + v3) * (1.f/256.f);
    float q  = (v0-mu)*(v0-mu) + (v1-mu)*(v1-mu) + (v2-mu)*(v2-mu) + (v3-mu)*(v3-mu);
    float rstd = rsqrtf(wsum(q) * (1.f/256.f) + 1e-5f);
    float4 g4 = *(const float4*)(lng + lane * 4);
    float4 bo = *(const float4*)(lnb + lane * 4);
    uint2 p;
    p.x = bf16u((v0-mu)*rstd*g4.x + bo.x) | (bf16u((v1-mu)*rstd*g4.y + bo.y) << 16);
    p.y = bf16u((v2-mu)*rstd*g4.z + bo.z) | (bf16u((v3-mu)*rstd*g4.w + bo.w) << 16);
    *(uint2*)(h1b + (size_t)wid * 256 + lane * 4) = p;
    return;
  }

  // slow path: deg > 64 (rare); lane = channel within head
  float m0 = -1e30f, m1 = -1e30f, m2 = -1e30f, m3 = -1e30f;
  for (int j = lane; j < deg; j += 64){
    int src = csr_src[s0 + j];
    float4 e4 = *(const float4*)(es + (size_t)src * 4);
    m0 = fmaxf(m0, lrelu(e4.x + edv.x));
    m1 = fmaxf(m1, lrelu(e4.y + edv.y));
    m2 = fmaxf(m2, lrelu(e4.z + edv.z));
    m3 = fmaxf(m3, lrelu(e4.w + edv.w));
  }
  m0 = wmaxr(m0); m1 = wmaxr(m1); m2 = wmaxr(m2); m3 = wmaxr(m3);
  float acc0 = 0.f, acc1 = 0.f, acc2 = 0.f, acc3 = 0.f;
  float den0 = 0.f, den1 = 0.f, den2 = 0.f, den3 = 0.f;
  for (int j = 0; j < deg; j++){
    int src = csr_src[s0 + j];
    float4 e4 = *(const float4*)(es + (size_t)src * 4);
    float x0 = __expf(lrelu(e4.x + edv.x) - m0);
    float x1 = __expf(lrelu(e4.y + edv.y) - m1);
    float x2 = __expf(lrelu(e4.z + edv.z) - m2);
    float x3 = __expf(lrelu(e4.w + edv.w) - m3);
    den0 += x0; den1 += x1; den2 += x2; den3 += x3;
    const unsigned short* hp = H1b + (size_t)src * 256;
    acc0 = fmaf(bfl(hp[lane]),       x0, acc0);
    acc1 = fmaf(bfl(hp[64 + lane]),  x1, acc1);
    acc2 = fmaf(bfl(hp[128 + lane]), x2, acc2);
    acc3 = fmaf(bfl(hp[192 + lane]), x3, acc3);
  }
  v0 = eluf(acc0 / (den0 + 1e-16f) + b1[lane]);
  v1 = eluf(acc1 / (den1 + 1e-16f) + b1[64 + lane]);
  v2 = eluf(acc2 / (den2 + 1e-16f) + b1[128 + lane]);
  v3 = eluf(acc3 / (den3 + 1e-16f) + b1[192 + lane]);
  float mu = wsum(v0 + v1 + v2 + v3) * (1.f/256.f);
  float q  = (v0-mu)*(v0-mu) + (v1-mu)*(v1-mu) + (v2-mu)*(v2-mu) + (v3-mu)*(v3-mu);
  float rstd = rsqrtf(wsum(q) * (1.f/256.f) + 1e-5f);
  unsigned short* o = h1b + (size_t)wid * 256;
  o[lane]       = (unsigned short)bf16u((v0-mu)*rstd*lng[lane]       + lnb[lane]);
  o[64 + lane]  = (unsigned short)bf16u((v1-mu)*rstd*lng[64 + lane]  + lnb[64 + lane]);
  o[128 + lane] = (unsigned short)bf16u((v2-mu)*rstd*lng[128 + lane] + lnb[128 + lane]);
  o[192 + lane] = (unsigned short)bf16u((v3-mu)*rstd*lng[192 + lane] + lnb[192 + lane]);
}

// ---------------- layer-2 aggregation (1 head, bf16 H2 gather) ----------------
__global__ __launch_bounds__(256) void agg2_kernel(const int* __restrict__ off,
                                                   const int* __restrict__ csr_src,
                                                   const int* __restrict__ csr_eid,
                                                   const unsigned short* __restrict__ H2b,
                                                   const float* __restrict__ es,
                                                   const float* __restrict__ ed,
                                                   const float* __restrict__ b2,
                                                   const float* __restrict__ lng,
                                                   const float* __restrict__ lnb,
                                                   float* __restrict__ h2out,
                                                   float* __restrict__ alpha_out, int n){
  int wid  = (blockIdx.x * blockDim.x + threadIdx.x) >> 6;
  int lane = threadIdx.x & 63;
  if (wid >= n) return;
  int s0  = off[wid];
  int deg = off[wid + 1] - s0;
  float edv = ed[wid];
  float acc = 0.f;

  if (deg <= 64){
    bool vld = lane < deg;
    int srcl = vld ? csr_src[s0 + lane] : 0;
    float el = vld ? lrelu(es[srcl] + edv) : -1e30f;
    float m  = wmaxr(el);
    float w  = vld ? __expf(el - m) : 0.f;
    float den = wsum(w) + 1e-16f;
    float wl = w / den;
    if (vld) alpha_out[csr_eid[s0 + lane]] = wl;
    int t = 0;
    for (; t + 4 <= deg; t += 4){
      int a0 = __shfl(srcl, t, 64),   a1 = __shfl(srcl, t+1, 64);
      int a2 = __shfl(srcl, t+2, 64), a3 = __shfl(srcl, t+3, 64);
      float q0 = __shfl(wl, t, 64),   q1 = __shfl(wl, t+1, 64);
      float q2 = __shfl(wl, t+2, 64), q3 = __shfl(wl, t+3, 64);
      float h0 = bfl(H2b[(size_t)a0 * 64 + lane]);
      float h1v = bfl(H2b[(size_t)a1 * 64 + lane]);
      float h2v = bfl(H2b[(size_t)a2 * 64 + lane]);
      float h3 = bfl(H2b[(size_t)a3 * 64 + lane]);
      acc = fmaf(h0, q0, acc); acc = fmaf(h1v, q1, acc);
      acc = fmaf(h2v, q2, acc); acc = fmaf(h3, q3, acc);
    }
    for (; t < deg; t++){
      int a0 = __shfl(srcl, t, 64);
      float q0 = __shfl(wl, t, 64);
      acc = fmaf(bfl(H2b[(size_t)a0 * 64 + lane]), q0, acc);
    }
  } else {
    float m = -1e30f;
    for (int j = lane; j < deg; j += 64){
      int src = csr_src[s0 + j];
      m = fmaxf(m, lrelu(es[src] + edv));
    }
    m = wmaxr(m);
    float den = 0.f;
    for (int j = lane; j < deg; j += 64){
      int src = csr_src[s0 + j];
      den += __expf(lrelu(es[src] + edv) - m);
    }
    den = wsum(den) + 1e-16f;
    for (int j = 0; j < deg; j++){
      int src = csr_src[s0 + j];
      float a = __expf(lrelu(es[src] + edv) - m) / den;
      if (lane == 0) alpha_out[csr_eid[s0 + j]] = a;
      acc = fmaf(bfl(H2b[(size_t)src * 64 + lane]), a, acc);
    }
  }
  float v  = acc + b2[lane];
  float mu = wsum(v) * (1.f/64.f);
  float d  = v - mu;
  float rstd = rsqrtf(wsum(d*d) * (1.f/64.f) + 1e-5f);
  h2out[(size_t)wid * 64 + lane] = d * rstd * lng[lane] + lnb[lane];
}

// ---------------- head: step/sentence MLP + dueling head ----------------
__global__ __launch_bounds__(64) void head_kernel(const float* __restrict__ semb,
                                                  const int* __restrict__ active,
                                                  const int* __restrict__ step,
                                                  const float* __restrict__ fc0w, const float* __restrict__ fc0b,
                                                  const float* __restrict__ fc1w, const float* __restrict__ fc1b,
                                                  const float* __restrict__ fc2w, const float* __restrict__ fc2b,
                                                  const float* __restrict__ fc3w, const float* __restrict__ fc3b,
                                                  const float* __restrict__ valw, const float* __restrict__ valb,
                                                  const float* __restrict__ advw, const float* __restrict__ advb,
                                                  const float* __restrict__ lnhg, const float* __restrict__ lnhb,
                                                  const float* __restrict__ lnfg, const float* __restrict__ lnfb,
                                                  const float* __restrict__ h2,
                                                  float* __restrict__ out){
  int t = threadIdx.x;  // one wave of 64
  __shared__ float sh[128];

  float sval = (float)(step[0] + 1) * 0.01f;
  float stepsv = ln64(fmaxf(fmaf(sval, fc0w[t], fc0b[t]), 0.f), lnhg, lnhb, t);

  float acc = fc1b[t];
  #pragma unroll 8
  for (int k = 0; k < 768; k++) acc = fmaf(semb[k], fc1w[k * 64 + t], acc);
  float sentv = ln64(fmaxf(acc, 0.f), lnhg, lnhb, t) + stepsv;
  sh[t] = sentv;
  __syncthreads();
  float acc2 = fc2b[t];
  #pragma unroll 8
  for (int k = 0; k < 64; k++) acc2 = fmaf(sh[k], fc2w[k * 64 + t], acc2);
  __syncthreads();
  float sent2 = ln64(fmaxf(acc2, 0.f), lnhg, lnhb, t);

  float a0 = h2[(size_t)active[0] * 64 + t];
  float a1 = sent2;
  float mu = wsum(a0 + a1) * (1.f/128.f);
  float q  = (a0-mu)*(a0-mu) + (a1-mu)*(a1-mu);
  float rstd = rsqrtf(wsum(q) * (1.f/128.f) + 1e-5f);
  float n0 = (a0-mu)*rstd*lnfg[t]      + lnfb[t];
  float n1 = (a1-mu)*rstd*lnfg[64 + t] + lnfb[64 + t];
  sh[t] = n0; sh[64 + t] = n1;
  __syncthreads();

  float acc3 = fc3b[t];
  #pragma unroll 8
  for (int k = 0; k < 128; k++) acc3 = fmaf(sh[k], fc3w[k * 64 + t], acc3);
  float a2v = ln64(fmaxf(acc3, 0.f), lnhg, lnhb, t);
  __syncthreads();
  sh[t] = a2v;
  __syncthreads();

  float val = wsum(a2v * valw[t]) + valb[0];
  float advv = 0.f;
  if (t < 32){
    advv = advb[t];
    #pragma unroll 8
    for (int k = 0; k < 64; k++) advv = fmaf(sh[k], advw[k * 32 + t], advv);
  }
  float am = wsum(t < 32 ? advv : 0.f) * (1.f/32.f);
  if (t < 32) out[t] = tanhf(val + advv - am);
}

extern "C" void kernel_launch(void* const* d_in, const int* in_sizes, int n_in,
                              void* d_out, int out_size, void* d_ws, size_t ws_size,
                              hipStream_t stream) {
  const float* x     = (const float*)d_in[0];
  const int*   ei    = (const int*)  d_in[1];
  const float* semb  = (const float*)d_in[2];
  const int*   act   = (const int*)  d_in[3];
  const int*   step  = (const int*)  d_in[4];
  const float* W1    = (const float*)d_in[5];
  const float* as1   = (const float*)d_in[6];
  const float* ad1   = (const float*)d_in[7];
  const float* b1    = (const float*)d_in[8];
  const float* W2    = (const float*)d_in[9];
  const float* as2   = (const float*)d_in[10];
  const float* ad2   = (const float*)d_in[11];
  const float* b2    = (const float*)d_in[12];
  const float* fc0w  = (const float*)d_in[13];
  const float* fc0b  = (const float*)d_in[14];
  const float* fc1w  = (const float*)d_in[15];
  const float* fc1b  = (const float*)d_in[16];
  const float* fc2w  = (const float*)d_in[17];
  const float* fc2b  = (const float*)d_in[18];
  const float* fc3w  = (const float*)d_in[19];
  const float* fc3b  = (const float*)d_in[20];
  const float* valw  = (const float*)d_in[21];
  const float* valb  = (const float*)d_in[22];
  const float* advw  = (const float*)d_in[23];
  const float* advb  = (const float*)d_in[24];
  const float* lnhg  = (const float*)d_in[25];
  const float* lnhb  = (const float*)d_in[26];
  const float* lnfg  = (const float*)d_in[27];
  const float* lnfb  = (const float*)d_in[28];
  const float* lnag  = (const float*)d_in[29];
  const float* lnab  = (const float*)d_in[30];

  char* ws = (char*)d_ws;
  size_t o = 0;
  auto alloc = [&](size_t bytes) -> void* {
    o = (o + 255) & ~(size_t)255;
    void* p = ws + o;
    o += bytes;
    return p;
  };
  int*   deg     = (int*)  alloc((size_t)(NN + 1) * 4);
  int*   off     = (int*)  alloc((size_t)(NN + 1) * 4);
  int*   cur     = (int*)  alloc((size_t)NN * 4);
  int*   bsum    = (int*)  alloc((size_t)(SCAN_NB + 1) * 4);
  int*   csr_src = (int*)  alloc((size_t)ET * 4);
  int*   csr_eid = (int*)  alloc((size_t)ET * 4);
  short* Wp1     = (short*)alloc((size_t)16 * 4 * 64 * 8 * 2);   // 64 KB
  short* Wp2     = (short*)alloc((size_t)4 * 8 * 64 * 8 * 2);    // 32 KB
  unsigned short* H1b = (unsigned short*)alloc((size_t)NN * 256 * 2);  // bf16 H1
  unsigned short* h1b = (unsigned short*)alloc((size_t)NN * 256 * 2);  // bf16 h1 (post agg1)
  float* es1     = (float*)alloc((size_t)NN * 16);
  float* ed1     = (float*)alloc((size_t)NN * 16);
  unsigned short* H2b = H1b;   // aliases; lifetimes don't overlap
  float* es2 = es1;
  float* ed2 = ed1;

  float* logits    = (float*)d_out;
  float* h2out     = (float*)d_out + 32;
  float* alpha_out = (float*)d_out + 32 + (size_t)NN * 64;

  // CSR build
  hipMemsetAsync(deg, 0, (size_t)NN * 4, stream);
  degree_kernel<<<(ET + 255) / 256, 256, 0, stream>>>(ei, deg);
  scan_part<<<SCAN_NB, 256, 0, stream>>>(deg, off, bsum, NN);
  scan_top <<<1, 64, 0, stream>>>(bsum, SCAN_NB);
  scan_add <<<SCAN_NB, 256, 0, stream>>>(off, cur, bsum, NN, SCAN_NB);
  fill_csr<<<(ET + 255) / 256, 256, 0, stream>>>(ei, cur, csr_src, csr_eid);

  // weight packs (tiny)
  pack_w<<<16, 256, 0, stream>>>(W1, Wp1, 128, 256);
  pack_w<<<8, 256, 0, stream>>>(W2, Wp2, 256, 64);

  // layer 1: MFMA GEMM + fused att dots
  mfma_gemm_att<4, 16, 4, true><<<(NN + 63) / 64, 256, 0, stream>>>(
      Wp1, x, nullptr, H1b, as1, ad1, es1, ed1, NN);
  agg1_kernel<<<NN / 4, 256, 0, stream>>>(off, csr_src, H1b, es1, ed1, b1, lnag, lnab, h1b, NN);

  // layer 2
  mfma_gemm_att<8, 4, 1, false><<<(NN + 63) / 64, 256, 0, stream>>>(
      Wp2, nullptr, h1b, H2b, as2, ad2, es2, ed2, NN);
  agg2_kernel<<<NN / 4, 256, 0, stream>>>(off, csr_src, csr_eid, H2b, es2, ed2, b2,
                                          lnhg, lnhb, h2out, alpha_out, NN);

  // head
  head_kernel<<<1, 64, 0, stream>>>(semb, act, step,
                                    fc0w, fc0b, fc1w, fc1b, fc2w, fc2b, fc3w, fc3b,
                                    valw, valb, advw, advb,
                                    lnhg, lnhb, lnfg, lnfb,
                                    h2out, logits);
}